// Round 4
// baseline (1232.995 us; speedup 1.0000x reference)
//
#include <hip/hip_runtime.h>
#include <cstdint>
#include <cstddef>

// B=2, S=2048, E=1024, H=16, HD=64; rows = 4096; heads = 32.
//
// GEMMs: bf16 hi/lo split-MFMA, 3 chunks (hi·hi + lo·hi + hi·lo; lo·lo ~2^-18
// dropped — validated in QK path r3).
// Attention: barrier-free MFMA kernel; Q/K/V fragments loaded directly from
// global (frag layout == 16x64B-segment read), P transform via wave-private
// LDS, coalesced float4 attn stores.

typedef __bf16 bf16x4 __attribute__((ext_vector_type(4)));
typedef __bf16 bf16x8 __attribute__((ext_vector_type(8)));
typedef float floatx4 __attribute__((ext_vector_type(4)));

#define GLOAD_LDS16(g, l)                                                      \
    __builtin_amdgcn_global_load_lds(                                          \
        (const __attribute__((address_space(1))) void*)(g),                    \
        (__attribute__((address_space(3))) void*)(l), 16, 0, 0)

// ------------------------------------------------------------------
// split_a: X fp32 (4096x1024, rm) -> Ap bf16 (4096x2048): [hi | lo] per row.
// ------------------------------------------------------------------
__global__ __launch_bounds__(256) void split_a(
    const float* __restrict__ x0, const float* __restrict__ x1,
    const float* __restrict__ x2, __bf16* __restrict__ ApBase)
{
    const float* X = blockIdx.z == 0 ? x0 : (blockIdx.z == 1 ? x1 : x2);
    __bf16* Ap = ApBase + (size_t)blockIdx.z * (4096ull * 2048);
    const int idx = blockIdx.x * 256 + threadIdx.x;
    const int r = idx >> 8;
    const int c = (idx & 255) * 4;
    float4 t = *(const float4*)(X + (size_t)r * 1024 + c);
    bf16x4 hi, lo;
    hi[0] = (__bf16)t.x; lo[0] = (__bf16)(t.x - (float)hi[0]);
    hi[1] = (__bf16)t.y; lo[1] = (__bf16)(t.y - (float)hi[1]);
    hi[2] = (__bf16)t.z; lo[2] = (__bf16)(t.z - (float)hi[2]);
    hi[3] = (__bf16)t.w; lo[3] = (__bf16)(t.w - (float)hi[3]);
    *(bf16x4*)(Ap + (size_t)r * 2048 + c) = hi;
    *(bf16x4*)(Ap + (size_t)r * 2048 + 1024 + c) = lo;
}

// ------------------------------------------------------------------
// split_bt: W fp32 (1024x1024 rm, [k][n]) -> Bp bf16 (1024x2048): row n holds
// [hi(W[:,n]) | lo(W[:,n])].
// ------------------------------------------------------------------
__global__ __launch_bounds__(256) void split_bt(
    const float* __restrict__ w0, const float* __restrict__ w1,
    const float* __restrict__ w2, __bf16* __restrict__ dstBase, size_t dstStride)
{
    const float* W = blockIdx.z == 0 ? w0 : (blockIdx.z == 1 ? w1 : w2);
    __bf16* Bp = dstBase + (size_t)blockIdx.z * dstStride;
    __shared__ float tile[64][65];
    const int tid = (int)threadIdx.x;
    const int k0 = blockIdx.y * 64, n0 = blockIdx.x * 64;
    #pragma unroll
    for (int p = 0; p < 4; ++p) {
        int kr = p * 16 + (tid >> 4);
        float4 t = *(const float4*)(W + (size_t)(k0 + kr) * 1024 + n0 + (tid & 15) * 4);
        tile[kr][(tid & 15) * 4 + 0] = t.x; tile[kr][(tid & 15) * 4 + 1] = t.y;
        tile[kr][(tid & 15) * 4 + 2] = t.z; tile[kr][(tid & 15) * 4 + 3] = t.w;
    }
    __syncthreads();
    const int nr = tid >> 2, kc = (tid & 3) * 16;
    bf16x8 hi0, hi1, lo0, lo1;
    #pragma unroll
    for (int j = 0; j < 8; ++j) {
        float x = tile[kc + j][nr];
        __bf16 h = (__bf16)x; hi0[j] = h; lo0[j] = (__bf16)(x - (float)h);
        float y = tile[kc + 8 + j][nr];
        __bf16 g = (__bf16)y; hi1[j] = g; lo1[j] = (__bf16)(y - (float)g);
    }
    __bf16* row = Bp + (size_t)(n0 + nr) * 2048;
    *(bf16x8*)(row + k0 + kc)          = hi0;
    *(bf16x8*)(row + k0 + kc + 8)      = hi1;
    *(bf16x8*)(row + 1024 + k0 + kc)     = lo0;
    *(bf16x8*)(row + 1024 + k0 + kc + 8) = lo1;
}

// ------------------------------------------------------------------
// gemm_split: C(4096x1024) = A*B (+bias), 3 hi/lo chunks, MFMA 16x16x32 bf16.
// ------------------------------------------------------------------
__global__ __launch_bounds__(256) void gemm_split(
    const __bf16* __restrict__ Ap0, const __bf16* __restrict__ Bp0,
    const float* __restrict__ b0, const float* __restrict__ b1,
    const float* __restrict__ b2, float* __restrict__ Out0,
    int transposeOut)
{
    const int z = blockIdx.z;
    const __bf16* Ap = Ap0 + (size_t)z * (4096ull * 2048);
    const __bf16* Bp = Bp0 + (size_t)z * (1024ull * 2048);
    const float* bias = z == 0 ? b0 : (z == 1 ? b1 : b2);
    float* Out = Out0 + (size_t)z * (4096ull * 1024);

    __shared__ __bf16 As[128 * 32];
    __shared__ __bf16 Bs[128 * 32];

    const int tid = (int)threadIdx.x;
    const int wave = tid >> 6, lane = tid & 63;
    const int quad = lane >> 4, tl = lane & 15;
    const int m0 = blockIdx.y * 128, n0 = blockIdx.x * 128;
    const int waveM = wave >> 1, waveN = wave & 1;

    floatx4 acc[4][4];
    #pragma unroll
    for (int i = 0; i < 4; ++i)
        #pragma unroll
        for (int j = 0; j < 4; ++j)
            acc[i][j] = (floatx4){0.f, 0.f, 0.f, 0.f};

    const int sRow  = (wave << 4) + (lane >> 2);
    const int sColB = (lane & 3) << 4;
    auto* AsL = (__attribute__((address_space(3))) char*)As;
    auto* BsL = (__attribute__((address_space(3))) char*)Bs;
    const int ldsOff = wave * 1024;

    // chunks: hi·hi, lo·hi, hi·lo (lo·lo dropped, ~2^-18)
    const int aOffs[3] = {0, 1024, 0};
    const int bOffs[3] = {0, 0, 1024};

    for (int ch = 0; ch < 3; ++ch) {
        const __bf16* Ach = Ap + aOffs[ch];
        const __bf16* Bch = Bp + bOffs[ch];
        for (int k0 = 0; k0 < 1024; k0 += 32) {
            __syncthreads();
            #pragma unroll
            for (int i = 0; i < 2; ++i) {
                GLOAD_LDS16(
                    (const char*)(Ach + (size_t)(m0 + i * 64 + sRow) * 2048 + k0) + sColB,
                    AsL + i * 4096 + ldsOff);
                GLOAD_LDS16(
                    (const char*)(Bch + (size_t)(n0 + i * 64 + sRow) * 2048 + k0) + sColB,
                    BsL + i * 4096 + ldsOff);
            }
            __syncthreads();

            bf16x8 af[4], bfr[4];
            #pragma unroll
            for (int mt = 0; mt < 4; ++mt)
                af[mt] = *(const bf16x8*)(As + (waveM * 64 + mt * 16 + tl) * 32 + quad * 8);
            #pragma unroll
            for (int nt = 0; nt < 4; ++nt)
                bfr[nt] = *(const bf16x8*)(Bs + (waveN * 64 + nt * 16 + tl) * 32 + quad * 8);
            #pragma unroll
            for (int mt = 0; mt < 4; ++mt)
                #pragma unroll
                for (int nt = 0; nt < 4; ++nt)
                    acc[mt][nt] = __builtin_amdgcn_mfma_f32_16x16x32_bf16(
                        af[mt], bfr[nt], acc[mt][nt], 0, 0, 0);
        }
    }

    if (transposeOut) {
        #pragma unroll
        for (int nt = 0; nt < 4; ++nt) {
            const int e = n0 + waveN * 64 + nt * 16 + tl;
            const float bb = bias[e];
            #pragma unroll
            for (int mt = 0; mt < 4; ++mt) {
                floatx4 v = acc[mt][nt] + bb;
                *(floatx4*)(Out + (size_t)e * 4096 + m0 + waveM * 64 + mt * 16 + quad * 4) = v;
            }
        }
    } else {
        #pragma unroll
        for (int mt = 0; mt < 4; ++mt) {
            const int rbase = m0 + waveM * 64 + mt * 16 + quad * 4;
            #pragma unroll
            for (int nt = 0; nt < 4; ++nt) {
                const int e = n0 + waveN * 64 + nt * 16 + tl;
                const float bb = bias[e];
                #pragma unroll
                for (int reg = 0; reg < 4; ++reg)
                    Out[(size_t)(rbase + reg) * 1024 + e] = acc[mt][nt][reg] + bb;
            }
        }
    }
}

// ------------------------------------------------------------------
// gather_qk: PT[e][4096] -> normalized head vectors, bf16 hi/lo.
// Outp[vec][128] = [hi(0..63) | lo(0..63)], vec = head*2048 + s'.
// ------------------------------------------------------------------
__global__ __launch_bounds__(256) void gather_qk(
    const float* __restrict__ PT, __bf16* __restrict__ Outp)
{
    const int tid  = (int)threadIdx.x;
    const int lane = tid & 63;
    const int vec  = blockIdx.x * 4 + (tid >> 6);
    const int head = vec >> 11;
    const int sp   = vec & 2047;
    const int c    = (head >> 4) * 512 + (head & 15) * 32 + (sp >> 6);
    const int src  = (lane & 1) * 2048 + (sp & 63) * 32 + (lane >> 1);
    float v = PT[(size_t)c * 4096 + src];
    float ss = v * v;
    #pragma unroll
    for (int mk = 32; mk >= 1; mk >>= 1) ss += __shfl_xor(ss, mk);
    v = v / sqrtf(ss);
    __bf16 h = (__bf16)v;
    Outp[(size_t)vec * 128 + lane]      = h;
    Outp[(size_t)vec * 128 + 64 + lane] = (__bf16)(v - (float)h);
}

// ------------------------------------------------------------------
// v_transpose: PTv[e][4096] -> Vt[head][d2=128][2048] bf16, d2 = d (hi) or
// 64+d (lo). One block per (64-s' tile, head).
// ------------------------------------------------------------------
__global__ __launch_bounds__(256) void v_transpose(
    const float* __restrict__ PTv, __bf16* __restrict__ Vt)
{
    const int head = blockIdx.y, st = blockIdx.x;
    const int tid = (int)threadIdx.x;
    const int c = (head >> 4) * 512 + (head & 15) * 32 + st;
    const float* __restrict__ row = PTv + (size_t)c * 4096;

    __shared__ float tile[64][65];   // [s'loc][d]
    #pragma unroll
    for (int i = 0; i < 4; ++i) {
        int o = i * 1024 + tid * 4;
        float4 t = *(const float4*)(row + o);
        float vals[4] = {t.x, t.y, t.z, t.w};
        #pragma unroll
        for (int e = 0; e < 4; ++e) {
            int oo = o + e;
            int d  = ((oo & 2047) & 31) * 2 + (oo >> 11);
            int sl = (oo & 2047) >> 5;
            tile[sl][d] = vals[e];
        }
    }
    __syncthreads();

    const int d = tid >> 2, jb = (tid & 3) * 16;
    bf16x8 h0, h1, l0, l1;
    #pragma unroll
    for (int j = 0; j < 8; ++j) {
        float x = tile[jb + j][d];
        __bf16 hh = (__bf16)x; h0[j] = hh; l0[j] = (__bf16)(x - (float)hh);
        float y = tile[jb + 8 + j][d];
        __bf16 gg = (__bf16)y; h1[j] = gg; l1[j] = (__bf16)(y - (float)gg);
    }
    size_t bh = ((size_t)head * 128 + d) * 2048 + st * 64 + jb;
    size_t bl = ((size_t)head * 128 + 64 + d) * 2048 + st * 64 + jb;
    *(bf16x8*)(Vt + bh)     = h0;
    *(bf16x8*)(Vt + bh + 8) = h1;
    *(bf16x8*)(Vt + bl)     = l0;
    *(bf16x8*)(Vt + bl + 8) = l1;
}

// ------------------------------------------------------------------
// attn_mfma: barrier-free. Block = (64 i-rows, head); 4 waves x 16 rows.
// Q/K/V frags loaded directly from global (16-row x 64B-segment pattern).
// Pass 1: online row max/expsum. Pass 2: recompute S, P -> wave-private LDS
// (bf16) -> coalesced float4 attn stores + A-frags for PV MFMA.
// Block swizzle head = flat&31 pins head -> XCD (flat%8 == head%8).
// ------------------------------------------------------------------
__global__ __launch_bounds__(256) void attn_mfma(
    const __bf16* __restrict__ Qp, const __bf16* __restrict__ Kp,
    const __bf16* __restrict__ Vt, float* __restrict__ Attn,
    __bf16* __restrict__ Az)
{
    const int flat = (int)blockIdx.x;
    const int head = flat & 31;
    const int it   = flat >> 5;
    const int tid = (int)threadIdx.x;
    const int w = tid >> 6, lane = tid & 63;
    const int quad = lane >> 4, tl = lane & 15;
    const int i0 = it * 64;

    const __bf16* __restrict__ Qh = Qp + ((size_t)head * 2048 + i0) * 128;
    const __bf16* __restrict__ Kh = Kp + (size_t)head * 2048 * 128;
    const __bf16* __restrict__ Vh = Vt + (size_t)head * 128 * 2048;
    float* __restrict__ Ah = Attn + (size_t)head * ((size_t)2048 * 2048);

    __shared__ __bf16 ps[4][16 * 72];   // wave-private P staging (C->A layout)
    __bf16* psw = ps[w];

    // ---- Q fragments direct from global (wave w owns rows w*16..w*16+15) ----
    const __bf16* qrow = Qh + (size_t)(w * 16 + tl) * 128;
    bf16x8 qhi0 = *(const bf16x8*)(qrow + quad * 8);
    bf16x8 qhi1 = *(const bf16x8*)(qrow + 32 + quad * 8);
    bf16x8 qlo0 = *(const bf16x8*)(qrow + 64 + quad * 8);
    bf16x8 qlo1 = *(const bf16x8*)(qrow + 96 + quad * 8);

    // ---- masked upper-triangle tiles: exact zeros, coalesced (1KB/instr) ----
    for (int jt = it + 1; jt < 32; ++jt) {
        float4 z4 = make_float4(0.f, 0.f, 0.f, 0.f);
        #pragma unroll
        for (int g = 0; g < 4; ++g)
            *(float4*)(Ah + (size_t)(i0 + w * 16 + g * 4 + quad) * 2048
                          + jt * 64 + tl * 4) = z4;
    }

    float m[4], l[4];
    #pragma unroll
    for (int r = 0; r < 4; ++r) { m[r] = -3.0e38f; l[r] = 0.0f; }

    // ---------- pass 1: stats (no LDS, no barriers) ----------
    for (int jt = 0; jt <= it; ++jt) {
        floatx4 S[4];
        #pragma unroll
        for (int sub = 0; sub < 4; ++sub) {
            const __bf16* kr = Kh + (size_t)(jt * 64 + sub * 16 + tl) * 128;
            bf16x8 khi0 = *(const bf16x8*)(kr + quad * 8);
            bf16x8 khi1 = *(const bf16x8*)(kr + 32 + quad * 8);
            bf16x8 klo0 = *(const bf16x8*)(kr + 64 + quad * 8);
            bf16x8 klo1 = *(const bf16x8*)(kr + 96 + quad * 8);
            floatx4 s = (floatx4){0.f, 0.f, 0.f, 0.f};
            s = __builtin_amdgcn_mfma_f32_16x16x32_bf16(qhi0, khi0, s, 0, 0, 0);
            s = __builtin_amdgcn_mfma_f32_16x16x32_bf16(qhi1, khi1, s, 0, 0, 0);
            s = __builtin_amdgcn_mfma_f32_16x16x32_bf16(qhi0, klo0, s, 0, 0, 0);
            s = __builtin_amdgcn_mfma_f32_16x16x32_bf16(qhi1, klo1, s, 0, 0, 0);
            s = __builtin_amdgcn_mfma_f32_16x16x32_bf16(qlo0, khi0, s, 0, 0, 0);
            s = __builtin_amdgcn_mfma_f32_16x16x32_bf16(qlo1, khi1, s, 0, 0, 0);
            S[sub] = s;
        }
        const bool diag = (jt == it);
        #pragma unroll
        for (int reg = 0; reg < 4; ++reg) {
            const int irow = w * 16 + quad * 4 + reg;
            float sl[4];
            #pragma unroll
            for (int sub = 0; sub < 4; ++sub) {
                float lv = S[sub][reg] * 1000.0f;
                if (diag && (sub * 16 + tl > irow)) lv = -1.0e9f;
                sl[sub] = lv;
            }
            float mt = fmaxf(fmaxf(sl[0], sl[1]), fmaxf(sl[2], sl[3]));
            float mn = fmaxf(m[reg], mt);
            l[reg] = l[reg] * __expf(m[reg] - mn)
                   + __expf(sl[0]-mn) + __expf(sl[1]-mn)
                   + __expf(sl[2]-mn) + __expf(sl[3]-mn);
            m[reg] = mn;
        }
    }

    // reduce stats across the 16 tl lanes (same quad = same rows)
    #pragma unroll
    for (int reg = 0; reg < 4; ++reg) {
        #pragma unroll
        for (int mk = 8; mk >= 1; mk >>= 1) {
            float mo = __shfl_xor(m[reg], mk);
            float lo = __shfl_xor(l[reg], mk);
            float mn = fmaxf(m[reg], mo);
            l[reg] = l[reg] * __expf(m[reg] - mn) + lo * __expf(mo - mn);
            m[reg] = mn;
        }
    }
    float inv_l[4];
    #pragma unroll
    for (int reg = 0; reg < 4; ++reg) inv_l[reg] = 1.0f / l[reg];

    // ---------- pass 2: attn write + PV ----------
    floatx4 zacc[4];
    #pragma unroll
    for (int t = 0; t < 4; ++t) zacc[t] = (floatx4){0.f, 0.f, 0.f, 0.f};

    for (int jt = 0; jt <= it; ++jt) {
        floatx4 S[4];
        #pragma unroll
        for (int sub = 0; sub < 4; ++sub) {
            const __bf16* kr = Kh + (size_t)(jt * 64 + sub * 16 + tl) * 128;
            bf16x8 khi0 = *(const bf16x8*)(kr + quad * 8);
            bf16x8 khi1 = *(const bf16x8*)(kr + 32 + quad * 8);
            bf16x8 klo0 = *(const bf16x8*)(kr + 64 + quad * 8);
            bf16x8 klo1 = *(const bf16x8*)(kr + 96 + quad * 8);
            floatx4 s = (floatx4){0.f, 0.f, 0.f, 0.f};
            s = __builtin_amdgcn_mfma_f32_16x16x32_bf16(qhi0, khi0, s, 0, 0, 0);
            s = __builtin_amdgcn_mfma_f32_16x16x32_bf16(qhi1, khi1, s, 0, 0, 0);
            s = __builtin_amdgcn_mfma_f32_16x16x32_bf16(qhi0, klo0, s, 0, 0, 0);
            s = __builtin_amdgcn_mfma_f32_16x16x32_bf16(qhi1, klo1, s, 0, 0, 0);
            s = __builtin_amdgcn_mfma_f32_16x16x32_bf16(qlo0, khi0, s, 0, 0, 0);
            s = __builtin_amdgcn_mfma_f32_16x16x32_bf16(qlo1, khi1, s, 0, 0, 0);
            S[sub] = s;
        }
        const bool diag = (jt == it);
        #pragma unroll
        for (int reg = 0; reg < 4; ++reg) {
            const int irow = w * 16 + quad * 4 + reg;
            #pragma unroll
            for (int sub = 0; sub < 4; ++sub) {
                float lv = S[sub][reg] * 1000.0f;
                if (diag && (sub * 16 + tl > irow)) lv = -1.0e9f;
                float p = __expf(lv - m[reg]) * inv_l[reg];
                psw[(quad * 4 + reg) * 72 + sub * 16 + tl] = (__bf16)p;
            }
        }
        // wave-private LDS: wait for writes to land (cross-lane read next)
        __asm__ volatile("s_waitcnt lgkmcnt(0)" ::: "memory");

        // coalesced attn stores: 4 x (b64 LDS read -> float4 global store)
        #pragma unroll
        for (int g = 0; g < 4; ++g) {
            bf16x4 pv = *(const bf16x4*)(psw + (g * 4 + quad) * 72 + tl * 4);
            float4 f = make_float4((float)pv[0], (float)pv[1],
                                   (float)pv[2], (float)pv[3]);
            *(float4*)(Ah + (size_t)(i0 + w * 16 + g * 4 + quad) * 2048
                          + jt * 64 + tl * 4) = f;
        }

        // P A-fragments
        bf16x8 p0 = *(const bf16x8*)(psw + tl * 72 + quad * 8);
        bf16x8 p1 = *(const bf16x8*)(psw + tl * 72 + 32 + quad * 8);

        // V fragments direct from global; PV MFMA
        #pragma unroll
        for (int t = 0; t < 4; ++t) {
            const __bf16* vh0 = Vh + (size_t)(t * 16 + tl) * 2048 + jt * 64;
            const __bf16* vl0 = Vh + (size_t)(64 + t * 16 + tl) * 2048 + jt * 64;
            bf16x8 vhi0 = *(const bf16x8*)(vh0 + quad * 8);
            bf16x8 vhi1 = *(const bf16x8*)(vh0 + 32 + quad * 8);
            bf16x8 vlo0 = *(const bf16x8*)(vl0 + quad * 8);
            bf16x8 vlo1 = *(const bf16x8*)(vl0 + 32 + quad * 8);
            zacc[t] = __builtin_amdgcn_mfma_f32_16x16x32_bf16(p0, vhi0, zacc[t], 0, 0, 0);
            zacc[t] = __builtin_amdgcn_mfma_f32_16x16x32_bf16(p1, vhi1, zacc[t], 0, 0, 0);
            zacc[t] = __builtin_amdgcn_mfma_f32_16x16x32_bf16(p0, vlo0, zacc[t], 0, 0, 0);
            zacc[t] = __builtin_amdgcn_mfma_f32_16x16x32_bf16(p1, vlo1, zacc[t], 0, 0, 0);
        }
    }

    // epilogue: z -> Az bf16 hi/lo (A-layout for out-GEMM)
    const int b = head >> 4, h = head & 15;
    #pragma unroll
    for (int reg = 0; reg < 4; ++reg) {
        const size_t R = (size_t)b * 2048 + i0 + w * 16 + quad * 4 + reg;
        #pragma unroll
        for (int t = 0; t < 4; ++t) {
            float x = zacc[t][reg];
            __bf16 hh = (__bf16)x;
            Az[R * 2048 + h * 64 + t * 16 + tl]        = hh;
            Az[R * 2048 + 1024 + h * 64 + t * 16 + tl] = (__bf16)(x - (float)hh);
        }
    }
}

// ------------------------------------------------------------------
extern "C" void kernel_launch(void* const* d_in, const int* in_sizes, int n_in,
                              void* d_out, int out_size, void* d_ws, size_t ws_size,
                              hipStream_t stream) {
    (void)in_sizes; (void)n_in; (void)out_size;
    const float* q  = (const float*)d_in[0];
    const float* k  = (const float*)d_in[1];
    const float* v  = (const float*)d_in[2];
    const float* Wq = (const float*)d_in[4];  const float* bq = (const float*)d_in[5];
    const float* Wk = (const float*)d_in[6];  const float* bk = (const float*)d_in[7];
    const float* Wv = (const float*)d_in[8];  const float* bv = (const float*)d_in[9];
    const float* Wz = (const float*)d_in[10]; const float* bz = (const float*)d_in[11];

    float* out0 = (float*)d_out;               // (2,2048,1024)
    float* attn = out0 + 4194304;              // (2,16,2048,2048) = 512 MB

    // Scratch in the not-yet-written attn region:
    float*  PT0 = attn;                                   // 3 x 4M floats
    __bf16* Ap0 = (__bf16*)(attn + 12582912);             // 3 x 4096x2048 bf16
    __bf16* Bp0 = (__bf16*)(attn + 12582912 + 12582912);  // 3 x 1024x2048 bf16

    // Wz split lives in Wq's buffer (consumed before this is written).
    __bf16* Bpz = (__bf16*)d_in[4];

    // Qp/Kp/Vt/Az bf16, 16 MB each. Prefer ws (64 MB); fallback clobbers
    // consumed inputs (restored by harness before every launch).
    __bf16 *Qp, *Kp, *Vtp, *Az;
    if (ws_size >= (size_t)67108864) {
        __bf16* ws = (__bf16*)d_ws;
        Qp = ws; Kp = ws + 8388608; Vtp = ws + 16777216; Az = ws + 25165824;
    } else {
        Qp = (__bf16*)d_in[0]; Kp = (__bf16*)d_in[1]; Vtp = (__bf16*)d_in[2];
        Az = (__bf16*)d_ws;
    }

    split_a <<<dim3(4096, 1, 3), 256, 0, stream>>>(q, k, v, Ap0);
    split_bt<<<dim3(16, 16, 3), 256, 0, stream>>>(Wq, Wk, Wv, Bp0, 1024ull*2048);

    gemm_split<<<dim3(8, 32, 3), 256, 0, stream>>>(Ap0, Bp0, bq, bk, bv, PT0, 1);

    gather_qk  <<<16384, 256, 0, stream>>>(PT0,           Qp);
    gather_qk  <<<16384, 256, 0, stream>>>(PT0 + 4194304, Kp);
    v_transpose<<<dim3(32, 32), 256, 0, stream>>>(PT0 + 8388608, Vtp);

    split_bt<<<dim3(16, 16, 1), 256, 0, stream>>>(Wz, Wz, Wz, Bpz, 0);

    attn_mfma<<<dim3(1024), 256, 0, stream>>>(Qp, Kp, Vtp, attn, Az);

    gemm_split<<<dim3(8, 32, 1), 256, 0, stream>>>(Az, Bpz, bz, bz, bz, out0, 0);
}

// Round 5
// 967.948 us; speedup vs baseline: 1.2738x; 1.2738x over previous
//
#include <hip/hip_runtime.h>
#include <cstdint>
#include <cstddef>

// B=2, S=2048, E=1024, H=16, HD=64; rows = 4096; heads = 32.
//
// GEMMs: bf16 hi/lo split-MFMA, 3 chunks (hi·hi + lo·hi + hi·lo).
// Attention: LDS-staged MFMA kernel. Tiles staged with global_load_lds
// (width 16) using an XOR chunk swizzle (c' = c ^ (row&7)) so fragment
// ds_read_b128s are ~conflict-free (2-way max) without padding (padding is
// incompatible with global_load_lds's lane-ordered LDS destination).

typedef __bf16 bf16x4 __attribute__((ext_vector_type(4)));
typedef __bf16 bf16x8 __attribute__((ext_vector_type(8)));
typedef float floatx4 __attribute__((ext_vector_type(4)));

#define GLOAD_LDS16(g, l)                                                      \
    __builtin_amdgcn_global_load_lds(                                          \
        (const __attribute__((address_space(1))) void*)(g),                    \
        (__attribute__((address_space(3))) void*)(l), 16, 0, 0)

// ------------------------------------------------------------------
// split_a: X fp32 (4096x1024, rm) -> Ap bf16 (4096x2048): [hi | lo] per row.
// ------------------------------------------------------------------
__global__ __launch_bounds__(256) void split_a(
    const float* __restrict__ x0, const float* __restrict__ x1,
    const float* __restrict__ x2, __bf16* __restrict__ ApBase)
{
    const float* X = blockIdx.z == 0 ? x0 : (blockIdx.z == 1 ? x1 : x2);
    __bf16* Ap = ApBase + (size_t)blockIdx.z * (4096ull * 2048);
    const int idx = blockIdx.x * 256 + threadIdx.x;
    const int r = idx >> 8;
    const int c = (idx & 255) * 4;
    float4 t = *(const float4*)(X + (size_t)r * 1024 + c);
    bf16x4 hi, lo;
    hi[0] = (__bf16)t.x; lo[0] = (__bf16)(t.x - (float)hi[0]);
    hi[1] = (__bf16)t.y; lo[1] = (__bf16)(t.y - (float)hi[1]);
    hi[2] = (__bf16)t.z; lo[2] = (__bf16)(t.z - (float)hi[2]);
    hi[3] = (__bf16)t.w; lo[3] = (__bf16)(t.w - (float)hi[3]);
    *(bf16x4*)(Ap + (size_t)r * 2048 + c) = hi;
    *(bf16x4*)(Ap + (size_t)r * 2048 + 1024 + c) = lo;
}

// ------------------------------------------------------------------
// split_bt: W fp32 (1024x1024 rm, [k][n]) -> Bp bf16 (1024x2048): row n holds
// [hi(W[:,n]) | lo(W[:,n])].
// ------------------------------------------------------------------
__global__ __launch_bounds__(256) void split_bt(
    const float* __restrict__ w0, const float* __restrict__ w1,
    const float* __restrict__ w2, __bf16* __restrict__ dstBase, size_t dstStride)
{
    const float* W = blockIdx.z == 0 ? w0 : (blockIdx.z == 1 ? w1 : w2);
    __bf16* Bp = dstBase + (size_t)blockIdx.z * dstStride;
    __shared__ float tile[64][65];
    const int tid = (int)threadIdx.x;
    const int k0 = blockIdx.y * 64, n0 = blockIdx.x * 64;
    #pragma unroll
    for (int p = 0; p < 4; ++p) {
        int kr = p * 16 + (tid >> 4);
        float4 t = *(const float4*)(W + (size_t)(k0 + kr) * 1024 + n0 + (tid & 15) * 4);
        tile[kr][(tid & 15) * 4 + 0] = t.x; tile[kr][(tid & 15) * 4 + 1] = t.y;
        tile[kr][(tid & 15) * 4 + 2] = t.z; tile[kr][(tid & 15) * 4 + 3] = t.w;
    }
    __syncthreads();
    const int nr = tid >> 2, kc = (tid & 3) * 16;
    bf16x8 hi0, hi1, lo0, lo1;
    #pragma unroll
    for (int j = 0; j < 8; ++j) {
        float x = tile[kc + j][nr];
        __bf16 h = (__bf16)x; hi0[j] = h; lo0[j] = (__bf16)(x - (float)h);
        float y = tile[kc + 8 + j][nr];
        __bf16 g = (__bf16)y; hi1[j] = g; lo1[j] = (__bf16)(y - (float)g);
    }
    __bf16* row = Bp + (size_t)(n0 + nr) * 2048;
    *(bf16x8*)(row + k0 + kc)          = hi0;
    *(bf16x8*)(row + k0 + kc + 8)      = hi1;
    *(bf16x8*)(row + 1024 + k0 + kc)     = lo0;
    *(bf16x8*)(row + 1024 + k0 + kc + 8) = lo1;
}

// ------------------------------------------------------------------
// gemm_split: C(4096x1024) = A*B (+bias), 3 hi/lo chunks, MFMA 16x16x32 bf16.
// ------------------------------------------------------------------
__global__ __launch_bounds__(256) void gemm_split(
    const __bf16* __restrict__ Ap0, const __bf16* __restrict__ Bp0,
    const float* __restrict__ b0, const float* __restrict__ b1,
    const float* __restrict__ b2, float* __restrict__ Out0,
    int transposeOut)
{
    const int z = blockIdx.z;
    const __bf16* Ap = Ap0 + (size_t)z * (4096ull * 2048);
    const __bf16* Bp = Bp0 + (size_t)z * (1024ull * 2048);
    const float* bias = z == 0 ? b0 : (z == 1 ? b1 : b2);
    float* Out = Out0 + (size_t)z * (4096ull * 1024);

    __shared__ __bf16 As[128 * 32];
    __shared__ __bf16 Bs[128 * 32];

    const int tid = (int)threadIdx.x;
    const int wave = tid >> 6, lane = tid & 63;
    const int quad = lane >> 4, tl = lane & 15;
    const int m0 = blockIdx.y * 128, n0 = blockIdx.x * 128;
    const int waveM = wave >> 1, waveN = wave & 1;

    floatx4 acc[4][4];
    #pragma unroll
    for (int i = 0; i < 4; ++i)
        #pragma unroll
        for (int j = 0; j < 4; ++j)
            acc[i][j] = (floatx4){0.f, 0.f, 0.f, 0.f};

    const int sRow  = (wave << 4) + (lane >> 2);
    const int sColB = (lane & 3) << 4;
    auto* AsL = (__attribute__((address_space(3))) char*)As;
    auto* BsL = (__attribute__((address_space(3))) char*)Bs;
    const int ldsOff = wave * 1024;

    // chunks: hi·hi, lo·hi, hi·lo (lo·lo dropped, ~2^-18)
    const int aOffs[3] = {0, 1024, 0};
    const int bOffs[3] = {0, 0, 1024};

    for (int ch = 0; ch < 3; ++ch) {
        const __bf16* Ach = Ap + aOffs[ch];
        const __bf16* Bch = Bp + bOffs[ch];
        for (int k0 = 0; k0 < 1024; k0 += 32) {
            __syncthreads();
            #pragma unroll
            for (int i = 0; i < 2; ++i) {
                GLOAD_LDS16(
                    (const char*)(Ach + (size_t)(m0 + i * 64 + sRow) * 2048 + k0) + sColB,
                    AsL + i * 4096 + ldsOff);
                GLOAD_LDS16(
                    (const char*)(Bch + (size_t)(n0 + i * 64 + sRow) * 2048 + k0) + sColB,
                    BsL + i * 4096 + ldsOff);
            }
            __syncthreads();

            bf16x8 af[4], bfr[4];
            #pragma unroll
            for (int mt = 0; mt < 4; ++mt)
                af[mt] = *(const bf16x8*)(As + (waveM * 64 + mt * 16 + tl) * 32 + quad * 8);
            #pragma unroll
            for (int nt = 0; nt < 4; ++nt)
                bfr[nt] = *(const bf16x8*)(Bs + (waveN * 64 + nt * 16 + tl) * 32 + quad * 8);
            #pragma unroll
            for (int mt = 0; mt < 4; ++mt)
                #pragma unroll
                for (int nt = 0; nt < 4; ++nt)
                    acc[mt][nt] = __builtin_amdgcn_mfma_f32_16x16x32_bf16(
                        af[mt], bfr[nt], acc[mt][nt], 0, 0, 0);
        }
    }

    if (transposeOut) {
        #pragma unroll
        for (int nt = 0; nt < 4; ++nt) {
            const int e = n0 + waveN * 64 + nt * 16 + tl;
            const float bb = bias[e];
            #pragma unroll
            for (int mt = 0; mt < 4; ++mt) {
                floatx4 v = acc[mt][nt] + bb;
                *(floatx4*)(Out + (size_t)e * 4096 + m0 + waveM * 64 + mt * 16 + quad * 4) = v;
            }
        }
    } else {
        #pragma unroll
        for (int mt = 0; mt < 4; ++mt) {
            const int rbase = m0 + waveM * 64 + mt * 16 + quad * 4;
            #pragma unroll
            for (int nt = 0; nt < 4; ++nt) {
                const int e = n0 + waveN * 64 + nt * 16 + tl;
                const float bb = bias[e];
                #pragma unroll
                for (int reg = 0; reg < 4; ++reg)
                    Out[(size_t)(rbase + reg) * 1024 + e] = acc[mt][nt][reg] + bb;
            }
        }
    }
}

// ------------------------------------------------------------------
// gather_qk: PT[e][4096] -> normalized head vectors, bf16 hi/lo.
// ------------------------------------------------------------------
__global__ __launch_bounds__(256) void gather_qk(
    const float* __restrict__ PT, __bf16* __restrict__ Outp)
{
    const int tid  = (int)threadIdx.x;
    const int lane = tid & 63;
    const int vec  = blockIdx.x * 4 + (tid >> 6);
    const int head = vec >> 11;
    const int sp   = vec & 2047;
    const int c    = (head >> 4) * 512 + (head & 15) * 32 + (sp >> 6);
    const int src  = (lane & 1) * 2048 + (sp & 63) * 32 + (lane >> 1);
    float v = PT[(size_t)c * 4096 + src];
    float ss = v * v;
    #pragma unroll
    for (int mk = 32; mk >= 1; mk >>= 1) ss += __shfl_xor(ss, mk);
    v = v / sqrtf(ss);
    __bf16 h = (__bf16)v;
    Outp[(size_t)vec * 128 + lane]      = h;
    Outp[(size_t)vec * 128 + 64 + lane] = (__bf16)(v - (float)h);
}

// ------------------------------------------------------------------
// v_transpose: PTv[e][4096] -> Vt[head][d2=128][2048] bf16.
// ------------------------------------------------------------------
__global__ __launch_bounds__(256) void v_transpose(
    const float* __restrict__ PTv, __bf16* __restrict__ Vt)
{
    const int head = blockIdx.y, st = blockIdx.x;
    const int tid = (int)threadIdx.x;
    const int c = (head >> 4) * 512 + (head & 15) * 32 + st;
    const float* __restrict__ row = PTv + (size_t)c * 4096;

    __shared__ float tile[64][65];   // [s'loc][d]
    #pragma unroll
    for (int i = 0; i < 4; ++i) {
        int o = i * 1024 + tid * 4;
        float4 t = *(const float4*)(row + o);
        float vals[4] = {t.x, t.y, t.z, t.w};
        #pragma unroll
        for (int e = 0; e < 4; ++e) {
            int oo = o + e;
            int d  = ((oo & 2047) & 31) * 2 + (oo >> 11);
            int sl = (oo & 2047) >> 5;
            tile[sl][d] = vals[e];
        }
    }
    __syncthreads();

    const int d = tid >> 2, jb = (tid & 3) * 16;
    bf16x8 h0, h1, l0, l1;
    #pragma unroll
    for (int j = 0; j < 8; ++j) {
        float x = tile[jb + j][d];
        __bf16 hh = (__bf16)x; h0[j] = hh; l0[j] = (__bf16)(x - (float)hh);
        float y = tile[jb + 8 + j][d];
        __bf16 gg = (__bf16)y; h1[j] = gg; l1[j] = (__bf16)(y - (float)gg);
    }
    size_t bh = ((size_t)head * 128 + d) * 2048 + st * 64 + jb;
    size_t bl = ((size_t)head * 128 + 64 + d) * 2048 + st * 64 + jb;
    *(bf16x8*)(Vt + bh)     = h0;
    *(bf16x8*)(Vt + bh + 8) = h1;
    *(bf16x8*)(Vt + bl)     = l0;
    *(bf16x8*)(Vt + bl + 8) = l1;
}

// ------------------------------------------------------------------
// attn_mfma: block = (64 i-rows, head); 4 waves x 16 rows.
// K/V tiles staged via global_load_lds with XOR chunk swizzle:
//   K tile: 64 rows x 16 chunks(16B); LDS chunk (r, c^(r&7)).
//   V tile: 128 rows x 8 chunks(16B); LDS chunk (r, c^(r&7)).
// Fragment ds_read_b128 then lands on 8 distinct bank groups (2-way = free).
// Heavy-first block order: it = 31 - (flat>>5).
// ------------------------------------------------------------------
__global__ __launch_bounds__(256) void attn_mfma(
    const __bf16* __restrict__ Qp, const __bf16* __restrict__ Kp,
    const __bf16* __restrict__ Vt, float* __restrict__ Attn,
    __bf16* __restrict__ Az)
{
    const int flat = (int)blockIdx.x;
    const int head = flat & 31;
    const int it   = 31 - (flat >> 5);     // heavy tiles dispatch first
    const int tid = (int)threadIdx.x;
    const int w = tid >> 6, lane = tid & 63;
    const int quad = lane >> 4, tl = lane & 15;
    const int t7 = tl & 7;
    const int i0 = it * 64;

    const __bf16* __restrict__ Qh = Qp + ((size_t)head * 2048 + i0) * 128;
    const __bf16* __restrict__ Kh = Kp + (size_t)head * 2048 * 128;
    const __bf16* __restrict__ Vh = Vt + (size_t)head * 128 * 2048;
    float* __restrict__ Ah = Attn + (size_t)head * ((size_t)2048 * 2048);

    __shared__ __bf16 kb[64 * 128];     // K tile, swizzled chunks (16 KB)
    __shared__ __bf16 vt[128 * 64];     // V^T tile, swizzled chunks (16 KB)
    __shared__ __bf16 ps[4][16 * 72];   // wave-private P staging (9 KB)
    __bf16* psw = ps[w];
    auto* kbL = (__attribute__((address_space(3))) char*)kb;
    auto* vtL = (__attribute__((address_space(3))) char*)vt;

    // per-lane staging sources (swizzled), constant across tiles
    const char* kSrc[4];
    const char* vSrc[4];
    #pragma unroll
    for (int i = 0; i < 4; ++i) {
        int d  = w * 256 + i * 64 + lane;
        int rK = d >> 4, cK = (d & 15) ^ (rK & 7);
        kSrc[i] = (const char*)(Kh + (size_t)rK * 128) + cK * 16;
        int rV = d >> 3, cV = (d & 7) ^ (rV & 7);
        vSrc[i] = (const char*)(Vh + (size_t)rV * 2048) + cV * 16;
    }
    // swizzled frag-read chunk offsets (bf16 elems), constant
    const int ok0 = ((quad)      ^ t7) * 8;
    const int ok1 = ((quad + 4)  ^ t7) * 8;
    const int ok2 = ((quad + 8)  ^ t7) * 8;
    const int ok3 = ((quad + 12) ^ t7) * 8;

    // ---- Q fragments direct from global (once per block) ----
    const __bf16* qrow = Qh + (size_t)(w * 16 + tl) * 128;
    bf16x8 qhi0 = *(const bf16x8*)(qrow + quad * 8);
    bf16x8 qhi1 = *(const bf16x8*)(qrow + 32 + quad * 8);
    bf16x8 qlo0 = *(const bf16x8*)(qrow + 64 + quad * 8);
    bf16x8 qlo1 = *(const bf16x8*)(qrow + 96 + quad * 8);

    // ---- masked upper-triangle tiles: exact zeros, coalesced ----
    for (int jt = it + 1; jt < 32; ++jt) {
        float4 z4 = make_float4(0.f, 0.f, 0.f, 0.f);
        #pragma unroll
        for (int g = 0; g < 4; ++g)
            *(float4*)(Ah + (size_t)(i0 + w * 16 + g * 4 + quad) * 2048
                          + jt * 64 + tl * 4) = z4;
    }

    float m[4], l[4];
    #pragma unroll
    for (int r = 0; r < 4; ++r) { m[r] = -3.0e38f; l[r] = 0.0f; }

    // ---------- pass 1: stats ----------
    for (int jt = 0; jt <= it; ++jt) {
        __syncthreads();   // frag reads of prior tile done
        #pragma unroll
        for (int i = 0; i < 4; ++i)
            GLOAD_LDS16(kSrc[i] + (size_t)jt * 16384, kbL + w * 4096 + i * 1024);
        __syncthreads();   // drains vmcnt: LDS valid

        floatx4 S[4];
        #pragma unroll
        for (int sub = 0; sub < 4; ++sub) {
            const __bf16* kr = kb + (sub * 16 + tl) * 128;
            bf16x8 khi0 = *(const bf16x8*)(kr + ok0);
            bf16x8 khi1 = *(const bf16x8*)(kr + ok1);
            bf16x8 klo0 = *(const bf16x8*)(kr + ok2);
            bf16x8 klo1 = *(const bf16x8*)(kr + ok3);
            floatx4 s = (floatx4){0.f, 0.f, 0.f, 0.f};
            s = __builtin_amdgcn_mfma_f32_16x16x32_bf16(qhi0, khi0, s, 0, 0, 0);
            s = __builtin_amdgcn_mfma_f32_16x16x32_bf16(qhi1, khi1, s, 0, 0, 0);
            s = __builtin_amdgcn_mfma_f32_16x16x32_bf16(qhi0, klo0, s, 0, 0, 0);
            s = __builtin_amdgcn_mfma_f32_16x16x32_bf16(qhi1, klo1, s, 0, 0, 0);
            s = __builtin_amdgcn_mfma_f32_16x16x32_bf16(qlo0, khi0, s, 0, 0, 0);
            s = __builtin_amdgcn_mfma_f32_16x16x32_bf16(qlo1, khi1, s, 0, 0, 0);
            S[sub] = s;
        }
        const bool diag = (jt == it);
        #pragma unroll
        for (int reg = 0; reg < 4; ++reg) {
            const int irow = w * 16 + quad * 4 + reg;
            float sl[4];
            #pragma unroll
            for (int sub = 0; sub < 4; ++sub) {
                float lv = S[sub][reg] * 1000.0f;
                if (diag && (sub * 16 + tl > irow)) lv = -1.0e9f;
                sl[sub] = lv;
            }
            float mt = fmaxf(fmaxf(sl[0], sl[1]), fmaxf(sl[2], sl[3]));
            float mn = fmaxf(m[reg], mt);
            l[reg] = l[reg] * __expf(m[reg] - mn)
                   + __expf(sl[0]-mn) + __expf(sl[1]-mn)
                   + __expf(sl[2]-mn) + __expf(sl[3]-mn);
            m[reg] = mn;
        }
    }

    // reduce stats across the 16 tl lanes
    #pragma unroll
    for (int reg = 0; reg < 4; ++reg) {
        #pragma unroll
        for (int mk = 8; mk >= 1; mk >>= 1) {
            float mo = __shfl_xor(m[reg], mk);
            float lo = __shfl_xor(l[reg], mk);
            float mn = fmaxf(m[reg], mo);
            l[reg] = l[reg] * __expf(m[reg] - mn) + lo * __expf(mo - mn);
            m[reg] = mn;
        }
    }
    float inv_l[4];
    #pragma unroll
    for (int reg = 0; reg < 4; ++reg) inv_l[reg] = 1.0f / l[reg];

    // ---------- pass 2: attn write + PV ----------
    floatx4 zacc[4];
    #pragma unroll
    for (int t = 0; t < 4; ++t) zacc[t] = (floatx4){0.f, 0.f, 0.f, 0.f};

    for (int jt = 0; jt <= it; ++jt) {
        __syncthreads();
        #pragma unroll
        for (int i = 0; i < 4; ++i) {
            GLOAD_LDS16(kSrc[i] + (size_t)jt * 16384, kbL + w * 4096 + i * 1024);
            GLOAD_LDS16(vSrc[i] + (size_t)jt * 128,   vtL + w * 4096 + i * 1024);
        }
        __syncthreads();

        floatx4 S[4];
        #pragma unroll
        for (int sub = 0; sub < 4; ++sub) {
            const __bf16* kr = kb + (sub * 16 + tl) * 128;
            bf16x8 khi0 = *(const bf16x8*)(kr + ok0);
            bf16x8 khi1 = *(const bf16x8*)(kr + ok1);
            bf16x8 klo0 = *(const bf16x8*)(kr + ok2);
            bf16x8 klo1 = *(const bf16x8*)(kr + ok3);
            floatx4 s = (floatx4){0.f, 0.f, 0.f, 0.f};
            s = __builtin_amdgcn_mfma_f32_16x16x32_bf16(qhi0, khi0, s, 0, 0, 0);
            s = __builtin_amdgcn_mfma_f32_16x16x32_bf16(qhi1, khi1, s, 0, 0, 0);
            s = __builtin_amdgcn_mfma_f32_16x16x32_bf16(qhi0, klo0, s, 0, 0, 0);
            s = __builtin_amdgcn_mfma_f32_16x16x32_bf16(qhi1, klo1, s, 0, 0, 0);
            s = __builtin_amdgcn_mfma_f32_16x16x32_bf16(qlo0, khi0, s, 0, 0, 0);
            s = __builtin_amdgcn_mfma_f32_16x16x32_bf16(qlo1, khi1, s, 0, 0, 0);
            S[sub] = s;
        }
        const bool diag = (jt == it);
        #pragma unroll
        for (int reg = 0; reg < 4; ++reg) {
            const int irow = w * 16 + quad * 4 + reg;
            #pragma unroll
            for (int sub = 0; sub < 4; ++sub) {
                float lv = S[sub][reg] * 1000.0f;
                if (diag && (sub * 16 + tl > irow)) lv = -1.0e9f;
                float p = __expf(lv - m[reg]) * inv_l[reg];
                psw[(quad * 4 + reg) * 72 + sub * 16 + tl] = (__bf16)p;
            }
        }
        // wave-private LDS: wait for writes to land (cross-lane reads next)
        __asm__ volatile("s_waitcnt lgkmcnt(0)" ::: "memory");

        // coalesced attn stores: 4 x (LDS b64 read -> float4 global store)
        #pragma unroll
        for (int g = 0; g < 4; ++g) {
            bf16x4 pv = *(const bf16x4*)(psw + (g * 4 + quad) * 72 + tl * 4);
            float4 f = make_float4((float)pv[0], (float)pv[1],
                                   (float)pv[2], (float)pv[3]);
            *(float4*)(Ah + (size_t)(i0 + w * 16 + g * 4 + quad) * 2048
                          + jt * 64 + tl * 4) = f;
        }

        // P A-fragments
        bf16x8 p0 = *(const bf16x8*)(psw + tl * 72 + quad * 8);
        bf16x8 p1 = *(const bf16x8*)(psw + tl * 72 + 32 + quad * 8);

        // V fragments from swizzled LDS tile; PV MFMA
        #pragma unroll
        for (int t = 0; t < 4; ++t) {
            const __bf16* vh0 = vt + (t * 16 + tl) * 64;
            const __bf16* vl0 = vt + (64 + t * 16 + tl) * 64;
            bf16x8 vhi0 = *(const bf16x8*)(vh0 + ok0);
            bf16x8 vhi1 = *(const bf16x8*)(vh0 + ok1);
            bf16x8 vlo0 = *(const bf16x8*)(vl0 + ok0);
            bf16x8 vlo1 = *(const bf16x8*)(vl0 + ok1);
            zacc[t] = __builtin_amdgcn_mfma_f32_16x16x32_bf16(p0, vhi0, zacc[t], 0, 0, 0);
            zacc[t] = __builtin_amdgcn_mfma_f32_16x16x32_bf16(p1, vhi1, zacc[t], 0, 0, 0);
            zacc[t] = __builtin_amdgcn_mfma_f32_16x16x32_bf16(p0, vlo0, zacc[t], 0, 0, 0);
            zacc[t] = __builtin_amdgcn_mfma_f32_16x16x32_bf16(p1, vlo1, zacc[t], 0, 0, 0);
        }
    }

    // epilogue: z -> Az bf16 hi/lo (A-layout for out-GEMM)
    const int b = head >> 4, h = head & 15;
    #pragma unroll
    for (int reg = 0; reg < 4; ++reg) {
        const size_t R = (size_t)b * 2048 + i0 + w * 16 + quad * 4 + reg;
        #pragma unroll
        for (int t = 0; t < 4; ++t) {
            float x = zacc[t][reg];
            __bf16 hh = (__bf16)x;
            Az[R * 2048 + h * 64 + t * 16 + tl]        = hh;
            Az[R * 2048 + 1024 + h * 64 + t * 16 + tl] = (__bf16)(x - (float)hh);
        }
    }
}

// ------------------------------------------------------------------
extern "C" void kernel_launch(void* const* d_in, const int* in_sizes, int n_in,
                              void* d_out, int out_size, void* d_ws, size_t ws_size,
                              hipStream_t stream) {
    (void)in_sizes; (void)n_in; (void)out_size;
    const float* q  = (const float*)d_in[0];
    const float* k  = (const float*)d_in[1];
    const float* v  = (const float*)d_in[2];
    const float* Wq = (const float*)d_in[4];  const float* bq = (const float*)d_in[5];
    const float* Wk = (const float*)d_in[6];  const float* bk = (const float*)d_in[7];
    const float* Wv = (const float*)d_in[8];  const float* bv = (const float*)d_in[9];
    const float* Wz = (const float*)d_in[10]; const float* bz = (const float*)d_in[11];

    float* out0 = (float*)d_out;               // (2,2048,1024)
    float* attn = out0 + 4194304;              // (2,16,2048,2048) = 512 MB

    // Scratch in the not-yet-written attn region:
    float*  PT0 = attn;                                   // 3 x 4M floats
    __bf16* Ap0 = (__bf16*)(attn + 12582912);             // 3 x 4096x2048 bf16
    __bf16* Bp0 = (__bf16*)(attn + 12582912 + 12582912);  // 3 x 1024x2048 bf16

    // Wz split lives in Wq's buffer (consumed before this is written).
    __bf16* Bpz = (__bf16*)d_in[4];

    // Qp/Kp/Vt/Az bf16, 16 MB each. Prefer ws (64 MB); fallback clobbers
    // consumed inputs (restored by harness before every launch).
    __bf16 *Qp, *Kp, *Vtp, *Az;
    if (ws_size >= (size_t)67108864) {
        __bf16* ws = (__bf16*)d_ws;
        Qp = ws; Kp = ws + 8388608; Vtp = ws + 16777216; Az = ws + 25165824;
    } else {
        Qp = (__bf16*)d_in[0]; Kp = (__bf16*)d_in[1]; Vtp = (__bf16*)d_in[2];
        Az = (__bf16*)d_ws;
    }

    split_a <<<dim3(4096, 1, 3), 256, 0, stream>>>(q, k, v, Ap0);
    split_bt<<<dim3(16, 16, 3), 256, 0, stream>>>(Wq, Wk, Wv, Bp0, 1024ull*2048);

    gemm_split<<<dim3(8, 32, 3), 256, 0, stream>>>(Ap0, Bp0, bq, bk, bv, PT0, 1);

    gather_qk  <<<16384, 256, 0, stream>>>(PT0,           Qp);
    gather_qk  <<<16384, 256, 0, stream>>>(PT0 + 4194304, Kp);
    v_transpose<<<dim3(32, 32), 256, 0, stream>>>(PT0 + 8388608, Vtp);

    split_bt<<<dim3(16, 16, 1), 256, 0, stream>>>(Wz, Wz, Wz, Bpz, 0);

    attn_mfma<<<dim3(1024), 256, 0, stream>>>(Qp, Kp, Vtp, attn, Az);

    gemm_split<<<dim3(8, 32, 1), 256, 0, stream>>>(Az, Bpz, bz, bz, bz, out0, 0);
}

// Round 6
// 889.244 us; speedup vs baseline: 1.3866x; 1.0885x over previous
//
#include <hip/hip_runtime.h>
#include <cstdint>
#include <cstddef>

// B=2, S=2048, E=1024, H=16, HD=64; rows = 4096; heads = 32.
//
// GEMMs: bf16 hi/lo split-MFMA, 3 chunks (hi·hi + lo·hi + hi·lo), FUSED into
// one K-loop: stage Ahi/Alo/Bhi/Blo per BK=32 step -> 48 MFMA per barrier
// pair (was 16), 4 slice-stagings (was 6), 64 barriers (was 192).
// Attention: 128-row i-tiles (512 thr, 8 waves), swizzled global_load_lds
// staging; wave-uniform fully-masked branches keep barriers uniform.

typedef __bf16 bf16x4 __attribute__((ext_vector_type(4)));
typedef __bf16 bf16x8 __attribute__((ext_vector_type(8)));
typedef float floatx4 __attribute__((ext_vector_type(4)));

#define GLOAD_LDS16(g, l)                                                      \
    __builtin_amdgcn_global_load_lds(                                          \
        (const __attribute__((address_space(1))) void*)(g),                    \
        (__attribute__((address_space(3))) void*)(l), 16, 0, 0)

// ------------------------------------------------------------------
// split_a: X fp32 (4096x1024, rm) -> Ap bf16 (4096x2048): [hi | lo] per row.
// ------------------------------------------------------------------
__global__ __launch_bounds__(256) void split_a(
    const float* __restrict__ x0, const float* __restrict__ x1,
    const float* __restrict__ x2, __bf16* __restrict__ ApBase)
{
    const float* X = blockIdx.z == 0 ? x0 : (blockIdx.z == 1 ? x1 : x2);
    __bf16* Ap = ApBase + (size_t)blockIdx.z * (4096ull * 2048);
    const int idx = blockIdx.x * 256 + threadIdx.x;
    const int r = idx >> 8;
    const int c = (idx & 255) * 4;
    float4 t = *(const float4*)(X + (size_t)r * 1024 + c);
    bf16x4 hi, lo;
    hi[0] = (__bf16)t.x; lo[0] = (__bf16)(t.x - (float)hi[0]);
    hi[1] = (__bf16)t.y; lo[1] = (__bf16)(t.y - (float)hi[1]);
    hi[2] = (__bf16)t.z; lo[2] = (__bf16)(t.z - (float)hi[2]);
    hi[3] = (__bf16)t.w; lo[3] = (__bf16)(t.w - (float)hi[3]);
    *(bf16x4*)(Ap + (size_t)r * 2048 + c) = hi;
    *(bf16x4*)(Ap + (size_t)r * 2048 + 1024 + c) = lo;
}

// ------------------------------------------------------------------
// split_bt: W fp32 (1024x1024 rm, [k][n]) -> Bp bf16 (1024x2048): row n holds
// [hi(W[:,n]) | lo(W[:,n])].
// ------------------------------------------------------------------
__global__ __launch_bounds__(256) void split_bt(
    const float* __restrict__ w0, const float* __restrict__ w1,
    const float* __restrict__ w2, __bf16* __restrict__ dstBase, size_t dstStride)
{
    const float* W = blockIdx.z == 0 ? w0 : (blockIdx.z == 1 ? w1 : w2);
    __bf16* Bp = dstBase + (size_t)blockIdx.z * dstStride;
    __shared__ float tile[64][65];
    const int tid = (int)threadIdx.x;
    const int k0 = blockIdx.y * 64, n0 = blockIdx.x * 64;
    #pragma unroll
    for (int p = 0; p < 4; ++p) {
        int kr = p * 16 + (tid >> 4);
        float4 t = *(const float4*)(W + (size_t)(k0 + kr) * 1024 + n0 + (tid & 15) * 4);
        tile[kr][(tid & 15) * 4 + 0] = t.x; tile[kr][(tid & 15) * 4 + 1] = t.y;
        tile[kr][(tid & 15) * 4 + 2] = t.z; tile[kr][(tid & 15) * 4 + 3] = t.w;
    }
    __syncthreads();
    const int nr = tid >> 2, kc = (tid & 3) * 16;
    bf16x8 hi0, hi1, lo0, lo1;
    #pragma unroll
    for (int j = 0; j < 8; ++j) {
        float x = tile[kc + j][nr];
        __bf16 h = (__bf16)x; hi0[j] = h; lo0[j] = (__bf16)(x - (float)h);
        float y = tile[kc + 8 + j][nr];
        __bf16 g = (__bf16)y; hi1[j] = g; lo1[j] = (__bf16)(y - (float)g);
    }
    __bf16* row = Bp + (size_t)(n0 + nr) * 2048;
    *(bf16x8*)(row + k0 + kc)          = hi0;
    *(bf16x8*)(row + k0 + kc + 8)      = hi1;
    *(bf16x8*)(row + 1024 + k0 + kc)     = lo0;
    *(bf16x8*)(row + 1024 + k0 + kc + 8) = lo1;
}

// ------------------------------------------------------------------
// gemm_split: C(4096x1024) = A*B (+bias); fused 3-chunk K-loop.
// 128x128 tile, BK=32, 4 waves (2x2), each wave 64x64 (4x4 MFMA tiles).
// ------------------------------------------------------------------
__global__ __launch_bounds__(256) void gemm_split(
    const __bf16* __restrict__ Ap0, const __bf16* __restrict__ Bp0,
    const float* __restrict__ b0, const float* __restrict__ b1,
    const float* __restrict__ b2, float* __restrict__ Out0,
    int transposeOut)
{
    const int z = blockIdx.z;
    const __bf16* Ap = Ap0 + (size_t)z * (4096ull * 2048);
    const __bf16* Bp = Bp0 + (size_t)z * (1024ull * 2048);
    const float* bias = z == 0 ? b0 : (z == 1 ? b1 : b2);
    float* Out = Out0 + (size_t)z * (4096ull * 1024);

    __shared__ __bf16 As[2 * 128 * 32];   // [hi | lo], rows of 64B
    __shared__ __bf16 Bs[2 * 128 * 32];

    const int tid = (int)threadIdx.x;
    const int wave = tid >> 6, lane = tid & 63;
    const int quad = lane >> 4, tl = lane & 15;
    const int m0 = blockIdx.y * 128, n0 = blockIdx.x * 128;
    const int waveM = wave >> 1, waveN = wave & 1;

    floatx4 acc[4][4];
    #pragma unroll
    for (int i = 0; i < 4; ++i)
        #pragma unroll
        for (int j = 0; j < 4; ++j)
            acc[i][j] = (floatx4){0.f, 0.f, 0.f, 0.f};

    const int sRow  = (wave << 4) + (lane >> 2);   // + i*64
    const int sColB = (lane & 3) << 4;
    auto* AsL = (__attribute__((address_space(3))) char*)As;
    auto* BsL = (__attribute__((address_space(3))) char*)Bs;
    const int ldsOff = wave * 1024;

    for (int k0 = 0; k0 < 1024; k0 += 32) {
        __syncthreads();
        #pragma unroll
        for (int i = 0; i < 2; ++i) {
            GLOAD_LDS16((const char*)(Ap + (size_t)(m0 + i*64 + sRow) * 2048 + k0) + sColB,
                        AsL + i * 4096 + ldsOff);
            GLOAD_LDS16((const char*)(Ap + 1024 + (size_t)(m0 + i*64 + sRow) * 2048 + k0) + sColB,
                        AsL + 8192 + i * 4096 + ldsOff);
            GLOAD_LDS16((const char*)(Bp + (size_t)(n0 + i*64 + sRow) * 2048 + k0) + sColB,
                        BsL + i * 4096 + ldsOff);
            GLOAD_LDS16((const char*)(Bp + 1024 + (size_t)(n0 + i*64 + sRow) * 2048 + k0) + sColB,
                        BsL + 8192 + i * 4096 + ldsOff);
        }
        __syncthreads();

        bf16x8 ah[4], bh[4], al[4], bl[4];
        #pragma unroll
        for (int mt = 0; mt < 4; ++mt)
            ah[mt] = *(const bf16x8*)(As + (waveM*64 + mt*16 + tl) * 32 + quad * 8);
        #pragma unroll
        for (int nt = 0; nt < 4; ++nt)
            bh[nt] = *(const bf16x8*)(Bs + (waveN*64 + nt*16 + tl) * 32 + quad * 8);
        #pragma unroll
        for (int mt = 0; mt < 4; ++mt)
            #pragma unroll
            for (int nt = 0; nt < 4; ++nt)
                acc[mt][nt] = __builtin_amdgcn_mfma_f32_16x16x32_bf16(
                    ah[mt], bh[nt], acc[mt][nt], 0, 0, 0);
        #pragma unroll
        for (int mt = 0; mt < 4; ++mt)
            al[mt] = *(const bf16x8*)(As + 4096 + (waveM*64 + mt*16 + tl) * 32 + quad * 8);
        #pragma unroll
        for (int mt = 0; mt < 4; ++mt)
            #pragma unroll
            for (int nt = 0; nt < 4; ++nt)
                acc[mt][nt] = __builtin_amdgcn_mfma_f32_16x16x32_bf16(
                    al[mt], bh[nt], acc[mt][nt], 0, 0, 0);
        #pragma unroll
        for (int nt = 0; nt < 4; ++nt)
            bl[nt] = *(const bf16x8*)(Bs + 4096 + (waveN*64 + nt*16 + tl) * 32 + quad * 8);
        #pragma unroll
        for (int mt = 0; mt < 4; ++mt)
            #pragma unroll
            for (int nt = 0; nt < 4; ++nt)
                acc[mt][nt] = __builtin_amdgcn_mfma_f32_16x16x32_bf16(
                    ah[mt], bl[nt], acc[mt][nt], 0, 0, 0);
    }

    if (transposeOut) {
        #pragma unroll
        for (int nt = 0; nt < 4; ++nt) {
            const int e = n0 + waveN * 64 + nt * 16 + tl;
            const float bb = bias[e];
            #pragma unroll
            for (int mt = 0; mt < 4; ++mt) {
                floatx4 v = acc[mt][nt] + bb;
                *(floatx4*)(Out + (size_t)e * 4096 + m0 + waveM * 64 + mt * 16 + quad * 4) = v;
            }
        }
    } else {
        #pragma unroll
        for (int mt = 0; mt < 4; ++mt) {
            const int rbase = m0 + waveM * 64 + mt * 16 + quad * 4;
            #pragma unroll
            for (int nt = 0; nt < 4; ++nt) {
                const int e = n0 + waveN * 64 + nt * 16 + tl;
                const float bb = bias[e];
                #pragma unroll
                for (int reg = 0; reg < 4; ++reg)
                    Out[(size_t)(rbase + reg) * 1024 + e] = acc[mt][nt][reg] + bb;
            }
        }
    }
}

// ------------------------------------------------------------------
// gather_qk: PT[e][4096] -> normalized head vectors, bf16 hi/lo.
// ------------------------------------------------------------------
__global__ __launch_bounds__(256) void gather_qk(
    const float* __restrict__ PT, __bf16* __restrict__ Outp)
{
    const int tid  = (int)threadIdx.x;
    const int lane = tid & 63;
    const int vec  = blockIdx.x * 4 + (tid >> 6);
    const int head = vec >> 11;
    const int sp   = vec & 2047;
    const int c    = (head >> 4) * 512 + (head & 15) * 32 + (sp >> 6);
    const int src  = (lane & 1) * 2048 + (sp & 63) * 32 + (lane >> 1);
    float v = PT[(size_t)c * 4096 + src];
    float ss = v * v;
    #pragma unroll
    for (int mk = 32; mk >= 1; mk >>= 1) ss += __shfl_xor(ss, mk);
    v = v / sqrtf(ss);
    __bf16 h = (__bf16)v;
    Outp[(size_t)vec * 128 + lane]      = h;
    Outp[(size_t)vec * 128 + 64 + lane] = (__bf16)(v - (float)h);
}

// ------------------------------------------------------------------
// v_transpose: PTv[e][4096] -> Vt[head][d2=128][2048] bf16.
// ------------------------------------------------------------------
__global__ __launch_bounds__(256) void v_transpose(
    const float* __restrict__ PTv, __bf16* __restrict__ Vt)
{
    const int head = blockIdx.y, st = blockIdx.x;
    const int tid = (int)threadIdx.x;
    const int c = (head >> 4) * 512 + (head & 15) * 32 + st;
    const float* __restrict__ row = PTv + (size_t)c * 4096;

    __shared__ float tile[64][65];   // [s'loc][d]
    #pragma unroll
    for (int i = 0; i < 4; ++i) {
        int o = i * 1024 + tid * 4;
        float4 t = *(const float4*)(row + o);
        float vals[4] = {t.x, t.y, t.z, t.w};
        #pragma unroll
        for (int e = 0; e < 4; ++e) {
            int oo = o + e;
            int d  = ((oo & 2047) & 31) * 2 + (oo >> 11);
            int sl = (oo & 2047) >> 5;
            tile[sl][d] = vals[e];
        }
    }
    __syncthreads();

    const int d = tid >> 2, jb = (tid & 3) * 16;
    bf16x8 h0, h1, l0, l1;
    #pragma unroll
    for (int j = 0; j < 8; ++j) {
        float x = tile[jb + j][d];
        __bf16 hh = (__bf16)x; h0[j] = hh; l0[j] = (__bf16)(x - (float)hh);
        float y = tile[jb + 8 + j][d];
        __bf16 gg = (__bf16)y; h1[j] = gg; l1[j] = (__bf16)(y - (float)gg);
    }
    size_t bh = ((size_t)head * 128 + d) * 2048 + st * 64 + jb;
    size_t bl = ((size_t)head * 128 + 64 + d) * 2048 + st * 64 + jb;
    *(bf16x8*)(Vt + bh)     = h0;
    *(bf16x8*)(Vt + bh + 8) = h1;
    *(bf16x8*)(Vt + bl)     = l0;
    *(bf16x8*)(Vt + bl + 8) = l1;
}

// ------------------------------------------------------------------
// attn_mfma: block = (128 i-rows, head); 8 waves x 16 rows, 512 threads.
// K/V tiles staged via global_load_lds with XOR chunk swizzle. Wave-uniform
// fully-masked branches (lower waves' diag is one tile earlier) keep all
// barriers uniform. Heavy-first: it = 15 - (flat>>5).
// ------------------------------------------------------------------
__global__ __launch_bounds__(512, 4) void attn_mfma(
    const __bf16* __restrict__ Qp, const __bf16* __restrict__ Kp,
    const __bf16* __restrict__ Vt, float* __restrict__ Attn,
    __bf16* __restrict__ Az)
{
    const int flat = (int)blockIdx.x;
    const int head = flat & 31;
    const int it   = 15 - (flat >> 5);     // heavy tiles dispatch first
    const int tid = (int)threadIdx.x;
    const int w = tid >> 6, lane = tid & 63;
    const int quad = lane >> 4, tl = lane & 15;
    const int t7 = tl & 7;
    const int i0 = it * 128;
    const int jtmax = 2 * it + 1;
    const int wrowMax = i0 + w * 16 + 15;          // wave's last row
    const int wdiag   = (i0 + w * 16) >> 6;        // wave's diagonal tile

    const __bf16* __restrict__ Qh = Qp + ((size_t)head * 2048 + i0) * 128;
    const __bf16* __restrict__ Kh = Kp + (size_t)head * 2048 * 128;
    const __bf16* __restrict__ Vh = Vt + (size_t)head * 128 * 2048;
    float* __restrict__ Ah = Attn + (size_t)head * ((size_t)2048 * 2048);

    __shared__ __bf16 kb[64 * 128];     // K tile, swizzled chunks (16 KB)
    __shared__ __bf16 vt[128 * 64];     // V^T tile, swizzled chunks (16 KB)
    __shared__ __bf16 ps[8][16 * 72];   // wave-private P staging (18 KB)
    __bf16* psw = ps[w];
    auto* kbL = (__attribute__((address_space(3))) char*)kb;
    auto* vtL = (__attribute__((address_space(3))) char*)vt;

    // per-lane staging sources (swizzled); 512 threads cover 16KB in 2 rounds
    const char* kSrc[2];
    const char* vSrc[2];
    #pragma unroll
    for (int i = 0; i < 2; ++i) {
        int d  = i * 512 + tid;
        int rK = d >> 4, cK = (d & 15) ^ (rK & 7);
        kSrc[i] = (const char*)(Kh + (size_t)rK * 128) + cK * 16;
        int rV = d >> 3, cV = (d & 7) ^ (rV & 7);
        vSrc[i] = (const char*)(Vh + (size_t)rV * 2048) + cV * 16;
    }
    // swizzled frag-read chunk offsets (bf16 elems)
    const int ok0 = ((quad)      ^ t7) * 8;
    const int ok1 = ((quad + 4)  ^ t7) * 8;
    const int ok2 = ((quad + 8)  ^ t7) * 8;
    const int ok3 = ((quad + 12) ^ t7) * 8;

    // ---- Q fragments direct from global (once per block) ----
    const __bf16* qrow = Qh + (size_t)(w * 16 + tl) * 128;
    bf16x8 qhi0 = *(const bf16x8*)(qrow + quad * 8);
    bf16x8 qhi1 = *(const bf16x8*)(qrow + 32 + quad * 8);
    bf16x8 qlo0 = *(const bf16x8*)(qrow + 64 + quad * 8);
    bf16x8 qlo1 = *(const bf16x8*)(qrow + 96 + quad * 8);

    // ---- tiles beyond jtmax: exact zeros (block-uniform range) ----
    for (int jt = jtmax + 1; jt < 32; ++jt) {
        float4 z4 = make_float4(0.f, 0.f, 0.f, 0.f);
        #pragma unroll
        for (int g = 0; g < 4; ++g)
            *(float4*)(Ah + (size_t)(i0 + w * 16 + g * 4 + quad) * 2048
                          + jt * 64 + tl * 4) = z4;
    }

    float m[4], l[4];
    #pragma unroll
    for (int r = 0; r < 4; ++r) { m[r] = -3.0e38f; l[r] = 0.0f; }

    // ---------- pass 1: stats ----------
    for (int jt = 0; jt <= jtmax; ++jt) {
        __syncthreads();
        #pragma unroll
        for (int i = 0; i < 2; ++i)
            GLOAD_LDS16(kSrc[i] + (size_t)jt * 16384, kbL + i * 8192 + w * 1024);
        __syncthreads();
        if (jt * 64 > wrowMax) continue;   // fully masked (wave-uniform)

        floatx4 S[4];
        #pragma unroll
        for (int sub = 0; sub < 4; ++sub) {
            const __bf16* kr = kb + (sub * 16 + tl) * 128;
            bf16x8 khi0 = *(const bf16x8*)(kr + ok0);
            bf16x8 khi1 = *(const bf16x8*)(kr + ok1);
            bf16x8 klo0 = *(const bf16x8*)(kr + ok2);
            bf16x8 klo1 = *(const bf16x8*)(kr + ok3);
            floatx4 s = (floatx4){0.f, 0.f, 0.f, 0.f};
            s = __builtin_amdgcn_mfma_f32_16x16x32_bf16(qhi0, khi0, s, 0, 0, 0);
            s = __builtin_amdgcn_mfma_f32_16x16x32_bf16(qhi1, khi1, s, 0, 0, 0);
            s = __builtin_amdgcn_mfma_f32_16x16x32_bf16(qhi0, klo0, s, 0, 0, 0);
            s = __builtin_amdgcn_mfma_f32_16x16x32_bf16(qhi1, klo1, s, 0, 0, 0);
            s = __builtin_amdgcn_mfma_f32_16x16x32_bf16(qlo0, khi0, s, 0, 0, 0);
            s = __builtin_amdgcn_mfma_f32_16x16x32_bf16(qlo1, khi1, s, 0, 0, 0);
            S[sub] = s;
        }
        const bool diag = (jt == wdiag);
        #pragma unroll
        for (int reg = 0; reg < 4; ++reg) {
            const int irow = w * 16 + quad * 4 + reg;   // local row (vs jt*64 local cols)
            float sl[4];
            #pragma unroll
            for (int sub = 0; sub < 4; ++sub) {
                float lv = S[sub][reg] * 1000.0f;
                if (diag && (jt * 64 + sub * 16 + tl > i0 + irow)) lv = -1.0e9f;
                sl[sub] = lv;
            }
            float mt = fmaxf(fmaxf(sl[0], sl[1]), fmaxf(sl[2], sl[3]));
            float mn = fmaxf(m[reg], mt);
            l[reg] = l[reg] * __expf(m[reg] - mn)
                   + __expf(sl[0]-mn) + __expf(sl[1]-mn)
                   + __expf(sl[2]-mn) + __expf(sl[3]-mn);
            m[reg] = mn;
        }
    }

    // reduce stats across the 16 tl lanes
    #pragma unroll
    for (int reg = 0; reg < 4; ++reg) {
        #pragma unroll
        for (int mk = 8; mk >= 1; mk >>= 1) {
            float mo = __shfl_xor(m[reg], mk);
            float lo = __shfl_xor(l[reg], mk);
            float mn = fmaxf(m[reg], mo);
            l[reg] = l[reg] * __expf(m[reg] - mn) + lo * __expf(mo - mn);
            m[reg] = mn;
        }
    }
    float inv_l[4];
    #pragma unroll
    for (int reg = 0; reg < 4; ++reg) inv_l[reg] = 1.0f / l[reg];

    // ---------- pass 2: attn write + PV ----------
    floatx4 zacc[4];
    #pragma unroll
    for (int t = 0; t < 4; ++t) zacc[t] = (floatx4){0.f, 0.f, 0.f, 0.f};

    for (int jt = 0; jt <= jtmax; ++jt) {
        __syncthreads();
        #pragma unroll
        for (int i = 0; i < 2; ++i) {
            GLOAD_LDS16(kSrc[i] + (size_t)jt * 16384, kbL + i * 8192 + w * 1024);
            GLOAD_LDS16(vSrc[i] + (size_t)jt * 128,   vtL + i * 8192 + w * 1024);
        }
        __syncthreads();

        if (jt * 64 > wrowMax) {   // fully masked: exact zeros (wave-uniform)
            float4 z4 = make_float4(0.f, 0.f, 0.f, 0.f);
            #pragma unroll
            for (int g = 0; g < 4; ++g)
                *(float4*)(Ah + (size_t)(i0 + w * 16 + g * 4 + quad) * 2048
                              + jt * 64 + tl * 4) = z4;
            continue;
        }

        floatx4 S[4];
        #pragma unroll
        for (int sub = 0; sub < 4; ++sub) {
            const __bf16* kr = kb + (sub * 16 + tl) * 128;
            bf16x8 khi0 = *(const bf16x8*)(kr + ok0);
            bf16x8 khi1 = *(const bf16x8*)(kr + ok1);
            bf16x8 klo0 = *(const bf16x8*)(kr + ok2);
            bf16x8 klo1 = *(const bf16x8*)(kr + ok3);
            floatx4 s = (floatx4){0.f, 0.f, 0.f, 0.f};
            s = __builtin_amdgcn_mfma_f32_16x16x32_bf16(qhi0, khi0, s, 0, 0, 0);
            s = __builtin_amdgcn_mfma_f32_16x16x32_bf16(qhi1, khi1, s, 0, 0, 0);
            s = __builtin_amdgcn_mfma_f32_16x16x32_bf16(qhi0, klo0, s, 0, 0, 0);
            s = __builtin_amdgcn_mfma_f32_16x16x32_bf16(qhi1, klo1, s, 0, 0, 0);
            s = __builtin_amdgcn_mfma_f32_16x16x32_bf16(qlo0, khi0, s, 0, 0, 0);
            s = __builtin_amdgcn_mfma_f32_16x16x32_bf16(qlo1, khi1, s, 0, 0, 0);
            S[sub] = s;
        }
        const bool diag = (jt == wdiag);
        #pragma unroll
        for (int reg = 0; reg < 4; ++reg) {
            const int irow = w * 16 + quad * 4 + reg;
            #pragma unroll
            for (int sub = 0; sub < 4; ++sub) {
                float lv = S[sub][reg] * 1000.0f;
                if (diag && (jt * 64 + sub * 16 + tl > i0 + irow)) lv = -1.0e9f;
                float p = __expf(lv - m[reg]) * inv_l[reg];
                psw[(quad * 4 + reg) * 72 + sub * 16 + tl] = (__bf16)p;
            }
        }
        // wave-private LDS: wait for writes to land (cross-lane reads next)
        __asm__ volatile("s_waitcnt lgkmcnt(0)" ::: "memory");

        // coalesced attn stores: 4 x (LDS b64 read -> float4 global store)
        #pragma unroll
        for (int g = 0; g < 4; ++g) {
            bf16x4 pv = *(const bf16x4*)(psw + (g * 4 + quad) * 72 + tl * 4);
            float4 f = make_float4((float)pv[0], (float)pv[1],
                                   (float)pv[2], (float)pv[3]);
            *(float4*)(Ah + (size_t)(i0 + w * 16 + g * 4 + quad) * 2048
                          + jt * 64 + tl * 4) = f;
        }

        // P A-fragments
        bf16x8 p0 = *(const bf16x8*)(psw + tl * 72 + quad * 8);
        bf16x8 p1 = *(const bf16x8*)(psw + tl * 72 + 32 + quad * 8);

        // V fragments from swizzled LDS tile; PV MFMA
        #pragma unroll
        for (int t = 0; t < 4; ++t) {
            const __bf16* vh0 = vt + (t * 16 + tl) * 64;
            const __bf16* vl0 = vt + (64 + t * 16 + tl) * 64;
            bf16x8 vhi0 = *(const bf16x8*)(vh0 + ok0);
            bf16x8 vhi1 = *(const bf16x8*)(vh0 + ok1);
            bf16x8 vlo0 = *(const bf16x8*)(vl0 + ok0);
            bf16x8 vlo1 = *(const bf16x8*)(vl0 + ok1);
            zacc[t] = __builtin_amdgcn_mfma_f32_16x16x32_bf16(p0, vhi0, zacc[t], 0, 0, 0);
            zacc[t] = __builtin_amdgcn_mfma_f32_16x16x32_bf16(p1, vhi1, zacc[t], 0, 0, 0);
            zacc[t] = __builtin_amdgcn_mfma_f32_16x16x32_bf16(p0, vlo0, zacc[t], 0, 0, 0);
            zacc[t] = __builtin_amdgcn_mfma_f32_16x16x32_bf16(p1, vlo1, zacc[t], 0, 0, 0);
        }
    }

    // epilogue: z -> Az bf16 hi/lo (A-layout for out-GEMM)
    const int b = head >> 4, h = head & 15;
    #pragma unroll
    for (int reg = 0; reg < 4; ++reg) {
        const size_t R = (size_t)b * 2048 + i0 + w * 16 + quad * 4 + reg;
        #pragma unroll
        for (int t = 0; t < 4; ++t) {
            float x = zacc[t][reg];
            __bf16 hh = (__bf16)x;
            Az[R * 2048 + h * 64 + t * 16 + tl]        = hh;
            Az[R * 2048 + 1024 + h * 64 + t * 16 + tl] = (__bf16)(x - (float)hh);
        }
    }
}

// ------------------------------------------------------------------
extern "C" void kernel_launch(void* const* d_in, const int* in_sizes, int n_in,
                              void* d_out, int out_size, void* d_ws, size_t ws_size,
                              hipStream_t stream) {
    (void)in_sizes; (void)n_in; (void)out_size;
    const float* q  = (const float*)d_in[0];
    const float* k  = (const float*)d_in[1];
    const float* v  = (const float*)d_in[2];
    const float* Wq = (const float*)d_in[4];  const float* bq = (const float*)d_in[5];
    const float* Wk = (const float*)d_in[6];  const float* bk = (const float*)d_in[7];
    const float* Wv = (const float*)d_in[8];  const float* bv = (const float*)d_in[9];
    const float* Wz = (const float*)d_in[10]; const float* bz = (const float*)d_in[11];

    float* out0 = (float*)d_out;               // (2,2048,1024)
    float* attn = out0 + 4194304;              // (2,16,2048,2048) = 512 MB

    // Scratch in the not-yet-written attn region:
    float*  PT0 = attn;                                   // 3 x 4M floats
    __bf16* Ap0 = (__bf16*)(attn + 12582912);             // 3 x 4096x2048 bf16
    __bf16* Bp0 = (__bf16*)(attn + 12582912 + 12582912);  // 3 x 1024x2048 bf16

    // Wz split lives in Wq's buffer (consumed before this is written).
    __bf16* Bpz = (__bf16*)d_in[4];

    // Qp/Kp/Vt/Az bf16, 16 MB each. Prefer ws (64 MB); fallback clobbers
    // consumed inputs (restored by harness before every launch).
    __bf16 *Qp, *Kp, *Vtp, *Az;
    if (ws_size >= (size_t)67108864) {
        __bf16* ws = (__bf16*)d_ws;
        Qp = ws; Kp = ws + 8388608; Vtp = ws + 16777216; Az = ws + 25165824;
    } else {
        Qp = (__bf16*)d_in[0]; Kp = (__bf16*)d_in[1]; Vtp = (__bf16*)d_in[2];
        Az = (__bf16*)d_ws;
    }

    split_a <<<dim3(4096, 1, 3), 256, 0, stream>>>(q, k, v, Ap0);
    split_bt<<<dim3(16, 16, 3), 256, 0, stream>>>(Wq, Wk, Wv, Bp0, 1024ull*2048);

    gemm_split<<<dim3(8, 32, 3), 256, 0, stream>>>(Ap0, Bp0, bq, bk, bv, PT0, 1);

    gather_qk  <<<16384, 256, 0, stream>>>(PT0,           Qp);
    gather_qk  <<<16384, 256, 0, stream>>>(PT0 + 4194304, Kp);
    v_transpose<<<dim3(32, 32), 256, 0, stream>>>(PT0 + 8388608, Vtp);

    split_bt<<<dim3(16, 16, 1), 256, 0, stream>>>(Wz, Wz, Wz, Bpz, 0);

    attn_mfma<<<dim3(512), 512, 0, stream>>>(Qp, Kp, Vtp, attn, Az);

    gemm_split<<<dim3(8, 32, 1), 256, 0, stream>>>(Az, Bpz, bz, bz, bz, out0, 0);
}

// Round 7
// 833.331 us; speedup vs baseline: 1.4796x; 1.0671x over previous
//
#include <hip/hip_runtime.h>
#include <cstdint>
#include <cstddef>

// B=2, S=2048, E=1024, H=16, HD=64; rows = 4096; heads = 32.
//
// Precision tiers (r7):
//  - Q/K projections + QK^T: bf16 hi/lo split, 3 chunks (cos needs ~1e-5
//    because logits = cos*1000).
//  - V projection, PV, out-GEMM: single bf16 chunk (no amplification;
//    P is already bf16 => ~0.4% floor).
// Attention: 128-row i-tiles (512 thr, 8 waves), swizzled global_load_lds
// staging, wave-uniform masked branches.

typedef __bf16 bf16x4 __attribute__((ext_vector_type(4)));
typedef __bf16 bf16x8 __attribute__((ext_vector_type(8)));
typedef float floatx4 __attribute__((ext_vector_type(4)));

#define GLOAD_LDS16(g, l)                                                      \
    __builtin_amdgcn_global_load_lds(                                          \
        (const __attribute__((address_space(1))) void*)(g),                    \
        (__attribute__((address_space(3))) void*)(l), 16, 0, 0)

// ------------------------------------------------------------------
// split_a: X fp32 (4096x1024, rm) -> Ap bf16 (4096x2048): [hi | lo] per row.
// ------------------------------------------------------------------
__global__ __launch_bounds__(256) void split_a(
    const float* __restrict__ x0, const float* __restrict__ x1,
    const float* __restrict__ x2, __bf16* __restrict__ ApBase)
{
    const float* X = blockIdx.z == 0 ? x0 : (blockIdx.z == 1 ? x1 : x2);
    __bf16* Ap = ApBase + (size_t)blockIdx.z * (4096ull * 2048);
    const int idx = blockIdx.x * 256 + threadIdx.x;
    const int r = idx >> 8;
    const int c = (idx & 255) * 4;
    float4 t = *(const float4*)(X + (size_t)r * 1024 + c);
    bf16x4 hi, lo;
    hi[0] = (__bf16)t.x; lo[0] = (__bf16)(t.x - (float)hi[0]);
    hi[1] = (__bf16)t.y; lo[1] = (__bf16)(t.y - (float)hi[1]);
    hi[2] = (__bf16)t.z; lo[2] = (__bf16)(t.z - (float)hi[2]);
    hi[3] = (__bf16)t.w; lo[3] = (__bf16)(t.w - (float)hi[3]);
    *(bf16x4*)(Ap + (size_t)r * 2048 + c) = hi;
    *(bf16x4*)(Ap + (size_t)r * 2048 + 1024 + c) = lo;
}

// ------------------------------------------------------------------
// split_bt: W fp32 (1024x1024 rm, [k][n]) -> Bp bf16 (1024x2048): row n holds
// [hi(W[:,n]) | lo(W[:,n])].
// ------------------------------------------------------------------
__global__ __launch_bounds__(256) void split_bt(
    const float* __restrict__ w0, const float* __restrict__ w1,
    const float* __restrict__ w2, __bf16* __restrict__ dstBase, size_t dstStride)
{
    const float* W = blockIdx.z == 0 ? w0 : (blockIdx.z == 1 ? w1 : w2);
    __bf16* Bp = dstBase + (size_t)blockIdx.z * dstStride;
    __shared__ float tile[64][65];
    const int tid = (int)threadIdx.x;
    const int k0 = blockIdx.y * 64, n0 = blockIdx.x * 64;
    #pragma unroll
    for (int p = 0; p < 4; ++p) {
        int kr = p * 16 + (tid >> 4);
        float4 t = *(const float4*)(W + (size_t)(k0 + kr) * 1024 + n0 + (tid & 15) * 4);
        tile[kr][(tid & 15) * 4 + 0] = t.x; tile[kr][(tid & 15) * 4 + 1] = t.y;
        tile[kr][(tid & 15) * 4 + 2] = t.z; tile[kr][(tid & 15) * 4 + 3] = t.w;
    }
    __syncthreads();
    const int nr = tid >> 2, kc = (tid & 3) * 16;
    bf16x8 hi0, hi1, lo0, lo1;
    #pragma unroll
    for (int j = 0; j < 8; ++j) {
        float x = tile[kc + j][nr];
        __bf16 h = (__bf16)x; hi0[j] = h; lo0[j] = (__bf16)(x - (float)h);
        float y = tile[kc + 8 + j][nr];
        __bf16 g = (__bf16)y; hi1[j] = g; lo1[j] = (__bf16)(y - (float)g);
    }
    __bf16* row = Bp + (size_t)(n0 + nr) * 2048;
    *(bf16x8*)(row + k0 + kc)          = hi0;
    *(bf16x8*)(row + k0 + kc + 8)      = hi1;
    *(bf16x8*)(row + 1024 + k0 + kc)     = lo0;
    *(bf16x8*)(row + 1024 + k0 + kc + 8) = lo1;
}

// ------------------------------------------------------------------
// gemm_split: C(4096x1024) = A*B (+bias); fused multi-chunk K-loop.
// nch per z: (z==2) ? chunksV : chunksQK. aStride: A row stride (bf16 elems);
// lo slice (nch>1) at A+1024 / B+1024.
// ------------------------------------------------------------------
__global__ __launch_bounds__(256) void gemm_split(
    const __bf16* __restrict__ Ap0, size_t aSlice, int aStride,
    const __bf16* __restrict__ Bp0, size_t bSlice,
    const float* __restrict__ b0, const float* __restrict__ b1,
    const float* __restrict__ b2, float* __restrict__ Out0,
    int transposeOut, int chunksQK, int chunksV)
{
    const int z = blockIdx.z;
    const int nch = (z == 2) ? chunksV : chunksQK;
    const __bf16* Ap = Ap0 + (size_t)z * aSlice;
    const __bf16* Bp = Bp0 + (size_t)z * bSlice;
    const float* bias = z == 0 ? b0 : (z == 1 ? b1 : b2);
    float* Out = Out0 + (size_t)z * (4096ull * 1024);

    __shared__ __bf16 As[2 * 128 * 32];   // [hi | lo], rows of 64B
    __shared__ __bf16 Bs[2 * 128 * 32];

    const int tid = (int)threadIdx.x;
    const int wave = tid >> 6, lane = tid & 63;
    const int quad = lane >> 4, tl = lane & 15;
    const int m0 = blockIdx.y * 128, n0 = blockIdx.x * 128;
    const int waveM = wave >> 1, waveN = wave & 1;

    floatx4 acc[4][4];
    #pragma unroll
    for (int i = 0; i < 4; ++i)
        #pragma unroll
        for (int j = 0; j < 4; ++j)
            acc[i][j] = (floatx4){0.f, 0.f, 0.f, 0.f};

    const int sRow  = (wave << 4) + (lane >> 2);   // + i*64
    const int sColB = (lane & 3) << 4;
    auto* AsL = (__attribute__((address_space(3))) char*)As;
    auto* BsL = (__attribute__((address_space(3))) char*)Bs;
    const int ldsOff = wave * 1024;

    for (int k0 = 0; k0 < 1024; k0 += 32) {
        __syncthreads();
        #pragma unroll
        for (int i = 0; i < 2; ++i) {
            GLOAD_LDS16((const char*)(Ap + (size_t)(m0 + i*64 + sRow) * aStride + k0) + sColB,
                        AsL + i * 4096 + ldsOff);
            GLOAD_LDS16((const char*)(Bp + (size_t)(n0 + i*64 + sRow) * 2048 + k0) + sColB,
                        BsL + i * 4096 + ldsOff);
            if (nch > 1) {
                GLOAD_LDS16((const char*)(Ap + 1024 + (size_t)(m0 + i*64 + sRow) * aStride + k0) + sColB,
                            AsL + 8192 + i * 4096 + ldsOff);
                GLOAD_LDS16((const char*)(Bp + 1024 + (size_t)(n0 + i*64 + sRow) * 2048 + k0) + sColB,
                            BsL + 8192 + i * 4096 + ldsOff);
            }
        }
        __syncthreads();

        bf16x8 ah[4], bh[4], al[4], bl[4];
        #pragma unroll
        for (int mt = 0; mt < 4; ++mt)
            ah[mt] = *(const bf16x8*)(As + (waveM*64 + mt*16 + tl) * 32 + quad * 8);
        #pragma unroll
        for (int nt = 0; nt < 4; ++nt)
            bh[nt] = *(const bf16x8*)(Bs + (waveN*64 + nt*16 + tl) * 32 + quad * 8);
        #pragma unroll
        for (int mt = 0; mt < 4; ++mt)
            #pragma unroll
            for (int nt = 0; nt < 4; ++nt)
                acc[mt][nt] = __builtin_amdgcn_mfma_f32_16x16x32_bf16(
                    ah[mt], bh[nt], acc[mt][nt], 0, 0, 0);
        if (nch > 1) {
            #pragma unroll
            for (int mt = 0; mt < 4; ++mt)
                al[mt] = *(const bf16x8*)(As + 4096 + (waveM*64 + mt*16 + tl) * 32 + quad * 8);
            #pragma unroll
            for (int mt = 0; mt < 4; ++mt)
                #pragma unroll
                for (int nt = 0; nt < 4; ++nt)
                    acc[mt][nt] = __builtin_amdgcn_mfma_f32_16x16x32_bf16(
                        al[mt], bh[nt], acc[mt][nt], 0, 0, 0);
        }
        if (nch > 2) {
            #pragma unroll
            for (int nt = 0; nt < 4; ++nt)
                bl[nt] = *(const bf16x8*)(Bs + 4096 + (waveN*64 + nt*16 + tl) * 32 + quad * 8);
            #pragma unroll
            for (int mt = 0; mt < 4; ++mt)
                #pragma unroll
                for (int nt = 0; nt < 4; ++nt)
                    acc[mt][nt] = __builtin_amdgcn_mfma_f32_16x16x32_bf16(
                        ah[mt], bl[nt], acc[mt][nt], 0, 0, 0);
        }
    }

    if (transposeOut) {
        #pragma unroll
        for (int nt = 0; nt < 4; ++nt) {
            const int e = n0 + waveN * 64 + nt * 16 + tl;
            const float bb = bias[e];
            #pragma unroll
            for (int mt = 0; mt < 4; ++mt) {
                floatx4 v = acc[mt][nt] + bb;
                *(floatx4*)(Out + (size_t)e * 4096 + m0 + waveM * 64 + mt * 16 + quad * 4) = v;
            }
        }
    } else {
        #pragma unroll
        for (int mt = 0; mt < 4; ++mt) {
            const int rbase = m0 + waveM * 64 + mt * 16 + quad * 4;
            #pragma unroll
            for (int nt = 0; nt < 4; ++nt) {
                const int e = n0 + waveN * 64 + nt * 16 + tl;
                const float bb = bias[e];
                #pragma unroll
                for (int reg = 0; reg < 4; ++reg)
                    Out[(size_t)(rbase + reg) * 1024 + e] = acc[mt][nt][reg] + bb;
            }
        }
    }
}

// ------------------------------------------------------------------
// gather_qk: PT[e][4096] -> normalized head vectors, bf16 hi/lo.
// ------------------------------------------------------------------
__global__ __launch_bounds__(256) void gather_qk(
    const float* __restrict__ PT, __bf16* __restrict__ Outp)
{
    const int tid  = (int)threadIdx.x;
    const int lane = tid & 63;
    const int vec  = blockIdx.x * 4 + (tid >> 6);
    const int head = vec >> 11;
    const int sp   = vec & 2047;
    const int c    = (head >> 4) * 512 + (head & 15) * 32 + (sp >> 6);
    const int src  = (lane & 1) * 2048 + (sp & 63) * 32 + (lane >> 1);
    float v = PT[(size_t)c * 4096 + src];
    float ss = v * v;
    #pragma unroll
    for (int mk = 32; mk >= 1; mk >>= 1) ss += __shfl_xor(ss, mk);
    v = v / sqrtf(ss);
    __bf16 h = (__bf16)v;
    Outp[(size_t)vec * 128 + lane]      = h;
    Outp[(size_t)vec * 128 + 64 + lane] = (__bf16)(v - (float)h);
}

// ------------------------------------------------------------------
// v_transpose: PTv[e][4096] -> Vt[head][d=64][2048] bf16 (hi only).
// ------------------------------------------------------------------
__global__ __launch_bounds__(256) void v_transpose(
    const float* __restrict__ PTv, __bf16* __restrict__ Vt)
{
    const int head = blockIdx.y, st = blockIdx.x;
    const int tid = (int)threadIdx.x;
    const int c = (head >> 4) * 512 + (head & 15) * 32 + st;
    const float* __restrict__ row = PTv + (size_t)c * 4096;

    __shared__ float tile[64][65];   // [s'loc][d]
    #pragma unroll
    for (int i = 0; i < 4; ++i) {
        int o = i * 1024 + tid * 4;
        float4 t = *(const float4*)(row + o);
        float vals[4] = {t.x, t.y, t.z, t.w};
        #pragma unroll
        for (int e = 0; e < 4; ++e) {
            int oo = o + e;
            int d  = ((oo & 2047) & 31) * 2 + (oo >> 11);
            int sl = (oo & 2047) >> 5;
            tile[sl][d] = vals[e];
        }
    }
    __syncthreads();

    const int d = tid >> 2, jb = (tid & 3) * 16;
    bf16x8 h0, h1;
    #pragma unroll
    for (int j = 0; j < 8; ++j) {
        h0[j] = (__bf16)tile[jb + j][d];
        h1[j] = (__bf16)tile[jb + 8 + j][d];
    }
    size_t bh = ((size_t)head * 64 + d) * 2048 + st * 64 + jb;
    *(bf16x8*)(Vt + bh)     = h0;
    *(bf16x8*)(Vt + bh + 8) = h1;
}

// ------------------------------------------------------------------
// attn_mfma: block = (128 i-rows, head); 8 waves x 16 rows, 512 threads.
// QK^T: 3-chunk hi/lo. PV: single chunk (V hi only). K/V tiles staged via
// global_load_lds with XOR chunk swizzle. Heavy-first: it = 15 - (flat>>5).
// ------------------------------------------------------------------
__global__ __launch_bounds__(512, 4) void attn_mfma(
    const __bf16* __restrict__ Qp, const __bf16* __restrict__ Kp,
    const __bf16* __restrict__ Vt, float* __restrict__ Attn,
    __bf16* __restrict__ Az)
{
    const int flat = (int)blockIdx.x;
    const int head = flat & 31;
    const int it   = 15 - (flat >> 5);     // heavy tiles dispatch first
    const int tid = (int)threadIdx.x;
    const int w = tid >> 6, lane = tid & 63;
    const int quad = lane >> 4, tl = lane & 15;
    const int t7 = tl & 7;
    const int i0 = it * 128;
    const int jtmax = 2 * it + 1;
    const int wrowMax = i0 + w * 16 + 15;          // wave's last row
    const int wdiag   = (i0 + w * 16) >> 6;        // wave's diagonal tile

    const __bf16* __restrict__ Qh = Qp + ((size_t)head * 2048 + i0) * 128;
    const __bf16* __restrict__ Kh = Kp + (size_t)head * 2048 * 128;
    const __bf16* __restrict__ Vh = Vt + (size_t)head * 64 * 2048;
    float* __restrict__ Ah = Attn + (size_t)head * ((size_t)2048 * 2048);

    __shared__ __bf16 kb[64 * 128];     // K tile, swizzled chunks (16 KB)
    __shared__ __bf16 vt[64 * 64];      // V^T tile (hi), swizzled (8 KB)
    __shared__ __bf16 ps[8][16 * 72];   // wave-private P staging (18 KB)
    __bf16* psw = ps[w];
    auto* kbL = (__attribute__((address_space(3))) char*)kb;
    auto* vtL = (__attribute__((address_space(3))) char*)vt;

    // per-lane staging sources (swizzled)
    const char* kSrc[2];
    #pragma unroll
    for (int i = 0; i < 2; ++i) {
        int d  = i * 512 + tid;
        int rK = d >> 4, cK = (d & 15) ^ (rK & 7);
        kSrc[i] = (const char*)(Kh + (size_t)rK * 128) + cK * 16;
    }
    const char* vSrc;
    {
        int rV = tid >> 3, cV = (tid & 7) ^ (rV & 7);
        vSrc = (const char*)(Vh + (size_t)rV * 2048) + cV * 16;
    }
    // swizzled frag-read chunk offsets (bf16 elems)
    const int ok0 = ((quad)      ^ t7) * 8;
    const int ok1 = ((quad + 4)  ^ t7) * 8;
    const int ok2 = ((quad + 8)  ^ t7) * 8;
    const int ok3 = ((quad + 12) ^ t7) * 8;

    // ---- Q fragments direct from global (once per block) ----
    const __bf16* qrow = Qh + (size_t)(w * 16 + tl) * 128;
    bf16x8 qhi0 = *(const bf16x8*)(qrow + quad * 8);
    bf16x8 qhi1 = *(const bf16x8*)(qrow + 32 + quad * 8);
    bf16x8 qlo0 = *(const bf16x8*)(qrow + 64 + quad * 8);
    bf16x8 qlo1 = *(const bf16x8*)(qrow + 96 + quad * 8);

    // ---- tiles beyond jtmax: exact zeros (block-uniform range) ----
    for (int jt = jtmax + 1; jt < 32; ++jt) {
        float4 z4 = make_float4(0.f, 0.f, 0.f, 0.f);
        #pragma unroll
        for (int g = 0; g < 4; ++g)
            *(float4*)(Ah + (size_t)(i0 + w * 16 + g * 4 + quad) * 2048
                          + jt * 64 + tl * 4) = z4;
    }

    float m[4], l[4];
    #pragma unroll
    for (int r = 0; r < 4; ++r) { m[r] = -3.0e38f; l[r] = 0.0f; }

    // ---------- pass 1: stats ----------
    for (int jt = 0; jt <= jtmax; ++jt) {
        __syncthreads();
        #pragma unroll
        for (int i = 0; i < 2; ++i)
            GLOAD_LDS16(kSrc[i] + (size_t)jt * 16384, kbL + i * 8192 + w * 1024);
        __syncthreads();
        if (jt * 64 > wrowMax) continue;   // fully masked (wave-uniform)

        floatx4 S[4];
        #pragma unroll
        for (int sub = 0; sub < 4; ++sub) {
            const __bf16* kr = kb + (sub * 16 + tl) * 128;
            bf16x8 khi0 = *(const bf16x8*)(kr + ok0);
            bf16x8 khi1 = *(const bf16x8*)(kr + ok1);
            bf16x8 klo0 = *(const bf16x8*)(kr + ok2);
            bf16x8 klo1 = *(const bf16x8*)(kr + ok3);
            floatx4 s = (floatx4){0.f, 0.f, 0.f, 0.f};
            s = __builtin_amdgcn_mfma_f32_16x16x32_bf16(qhi0, khi0, s, 0, 0, 0);
            s = __builtin_amdgcn_mfma_f32_16x16x32_bf16(qhi1, khi1, s, 0, 0, 0);
            s = __builtin_amdgcn_mfma_f32_16x16x32_bf16(qhi0, klo0, s, 0, 0, 0);
            s = __builtin_amdgcn_mfma_f32_16x16x32_bf16(qhi1, klo1, s, 0, 0, 0);
            s = __builtin_amdgcn_mfma_f32_16x16x32_bf16(qlo0, khi0, s, 0, 0, 0);
            s = __builtin_amdgcn_mfma_f32_16x16x32_bf16(qlo1, khi1, s, 0, 0, 0);
            S[sub] = s;
        }
        const bool diag = (jt == wdiag);
        #pragma unroll
        for (int reg = 0; reg < 4; ++reg) {
            const int irow = w * 16 + quad * 4 + reg;
            float sl[4];
            #pragma unroll
            for (int sub = 0; sub < 4; ++sub) {
                float lv = S[sub][reg] * 1000.0f;
                if (diag && (jt * 64 + sub * 16 + tl > i0 + irow)) lv = -1.0e9f;
                sl[sub] = lv;
            }
            float mt = fmaxf(fmaxf(sl[0], sl[1]), fmaxf(sl[2], sl[3]));
            float mn = fmaxf(m[reg], mt);
            l[reg] = l[reg] * __expf(m[reg] - mn)
                   + __expf(sl[0]-mn) + __expf(sl[1]-mn)
                   + __expf(sl[2]-mn) + __expf(sl[3]-mn);
            m[reg] = mn;
        }
    }

    // reduce stats across the 16 tl lanes
    #pragma unroll
    for (int reg = 0; reg < 4; ++reg) {
        #pragma unroll
        for (int mk = 8; mk >= 1; mk >>= 1) {
            float mo = __shfl_xor(m[reg], mk);
            float lo = __shfl_xor(l[reg], mk);
            float mn = fmaxf(m[reg], mo);
            l[reg] = l[reg] * __expf(m[reg] - mn) + lo * __expf(mo - mn);
            m[reg] = mn;
        }
    }
    float inv_l[4];
    #pragma unroll
    for (int reg = 0; reg < 4; ++reg) inv_l[reg] = 1.0f / l[reg];

    // ---------- pass 2: attn write + PV ----------
    floatx4 zacc[4];
    #pragma unroll
    for (int t = 0; t < 4; ++t) zacc[t] = (floatx4){0.f, 0.f, 0.f, 0.f};

    for (int jt = 0; jt <= jtmax; ++jt) {
        __syncthreads();
        #pragma unroll
        for (int i = 0; i < 2; ++i)
            GLOAD_LDS16(kSrc[i] + (size_t)jt * 16384, kbL + i * 8192 + w * 1024);
        GLOAD_LDS16(vSrc + (size_t)jt * 128, vtL + w * 1024);
        __syncthreads();

        if (jt * 64 > wrowMax) {   // fully masked: exact zeros (wave-uniform)
            float4 z4 = make_float4(0.f, 0.f, 0.f, 0.f);
            #pragma unroll
            for (int g = 0; g < 4; ++g)
                *(float4*)(Ah + (size_t)(i0 + w * 16 + g * 4 + quad) * 2048
                              + jt * 64 + tl * 4) = z4;
            continue;
        }

        floatx4 S[4];
        #pragma unroll
        for (int sub = 0; sub < 4; ++sub) {
            const __bf16* kr = kb + (sub * 16 + tl) * 128;
            bf16x8 khi0 = *(const bf16x8*)(kr + ok0);
            bf16x8 khi1 = *(const bf16x8*)(kr + ok1);
            bf16x8 klo0 = *(const bf16x8*)(kr + ok2);
            bf16x8 klo1 = *(const bf16x8*)(kr + ok3);
            floatx4 s = (floatx4){0.f, 0.f, 0.f, 0.f};
            s = __builtin_amdgcn_mfma_f32_16x16x32_bf16(qhi0, khi0, s, 0, 0, 0);
            s = __builtin_amdgcn_mfma_f32_16x16x32_bf16(qhi1, khi1, s, 0, 0, 0);
            s = __builtin_amdgcn_mfma_f32_16x16x32_bf16(qhi0, klo0, s, 0, 0, 0);
            s = __builtin_amdgcn_mfma_f32_16x16x32_bf16(qhi1, klo1, s, 0, 0, 0);
            s = __builtin_amdgcn_mfma_f32_16x16x32_bf16(qlo0, khi0, s, 0, 0, 0);
            s = __builtin_amdgcn_mfma_f32_16x16x32_bf16(qlo1, khi1, s, 0, 0, 0);
            S[sub] = s;
        }
        const bool diag = (jt == wdiag);
        #pragma unroll
        for (int reg = 0; reg < 4; ++reg) {
            const int irow = w * 16 + quad * 4 + reg;
            #pragma unroll
            for (int sub = 0; sub < 4; ++sub) {
                float lv = S[sub][reg] * 1000.0f;
                if (diag && (jt * 64 + sub * 16 + tl > i0 + irow)) lv = -1.0e9f;
                float p = __expf(lv - m[reg]) * inv_l[reg];
                psw[(quad * 4 + reg) * 72 + sub * 16 + tl] = (__bf16)p;
            }
        }
        // wave-private LDS: wait for writes to land (cross-lane reads next)
        __asm__ volatile("s_waitcnt lgkmcnt(0)" ::: "memory");

        // coalesced attn stores: 4 x (LDS b64 read -> float4 global store)
        #pragma unroll
        for (int g = 0; g < 4; ++g) {
            bf16x4 pv = *(const bf16x4*)(psw + (g * 4 + quad) * 72 + tl * 4);
            float4 f = make_float4((float)pv[0], (float)pv[1],
                                   (float)pv[2], (float)pv[3]);
            *(float4*)(Ah + (size_t)(i0 + w * 16 + g * 4 + quad) * 2048
                          + jt * 64 + tl * 4) = f;
        }

        // P A-fragments
        bf16x8 p0 = *(const bf16x8*)(psw + tl * 72 + quad * 8);
        bf16x8 p1 = *(const bf16x8*)(psw + tl * 72 + 32 + quad * 8);

        // V fragments (hi only) from swizzled LDS tile; PV MFMA
        #pragma unroll
        for (int t = 0; t < 4; ++t) {
            const __bf16* vh0 = vt + (t * 16 + tl) * 64;
            bf16x8 vhi0 = *(const bf16x8*)(vh0 + ok0);
            bf16x8 vhi1 = *(const bf16x8*)(vh0 + ok1);
            zacc[t] = __builtin_amdgcn_mfma_f32_16x16x32_bf16(p0, vhi0, zacc[t], 0, 0, 0);
            zacc[t] = __builtin_amdgcn_mfma_f32_16x16x32_bf16(p1, vhi1, zacc[t], 0, 0, 0);
        }
    }

    // epilogue: z -> Az bf16 (single chunk), A-layout row R, col h*64+d
    const int b = head >> 4, h = head & 15;
    #pragma unroll
    for (int reg = 0; reg < 4; ++reg) {
        const size_t R = (size_t)b * 2048 + i0 + w * 16 + quad * 4 + reg;
        #pragma unroll
        for (int t = 0; t < 4; ++t)
            Az[R * 1024 + h * 64 + t * 16 + tl] = (__bf16)zacc[t][reg];
    }
}

// ------------------------------------------------------------------
extern "C" void kernel_launch(void* const* d_in, const int* in_sizes, int n_in,
                              void* d_out, int out_size, void* d_ws, size_t ws_size,
                              hipStream_t stream) {
    (void)in_sizes; (void)n_in; (void)out_size;
    const float* q  = (const float*)d_in[0];
    const float* k  = (const float*)d_in[1];
    const float* v  = (const float*)d_in[2];
    const float* Wq = (const float*)d_in[4];  const float* bq = (const float*)d_in[5];
    const float* Wk = (const float*)d_in[6];  const float* bk = (const float*)d_in[7];
    const float* Wv = (const float*)d_in[8];  const float* bv = (const float*)d_in[9];
    const float* Wz = (const float*)d_in[10]; const float* bz = (const float*)d_in[11];

    float* out0 = (float*)d_out;               // (2,2048,1024)
    float* attn = out0 + 4194304;              // (2,16,2048,2048) = 512 MB

    // Scratch in the not-yet-written attn region:
    float*  PT0 = attn;                                   // 3 x 4M floats
    __bf16* Ap0 = (__bf16*)(attn + 12582912);             // 3 x 4096x2048 bf16
    __bf16* Bp0 = (__bf16*)(attn + 12582912 + 12582912);  // 3 x 1024x2048 bf16

    // Wz split lives in Wq's buffer (consumed before this is written).
    __bf16* Bpz = (__bf16*)d_in[4];

    // Qp(16MB) Kp(16MB) Vt(8MB) Az(8MB). Prefer ws; fallback clobbers
    // consumed inputs (restored by harness before every launch).
    __bf16 *Qp, *Kp, *Vtp, *Az;
    if (ws_size >= (size_t)50331648) {
        __bf16* ws = (__bf16*)d_ws;
        Qp = ws; Kp = ws + 8388608; Vtp = ws + 16777216; Az = ws + 20971520;
    } else {
        Qp = (__bf16*)d_in[0]; Kp = (__bf16*)d_in[1]; Vtp = (__bf16*)d_in[2];
        Az = (__bf16*)d_ws;
    }

    split_a <<<dim3(4096, 1, 3), 256, 0, stream>>>(q, k, v, Ap0);
    split_bt<<<dim3(16, 16, 3), 256, 0, stream>>>(Wq, Wk, Wv, Bp0, 1024ull*2048);

    // projections: Q/K 3-chunk, V 1-chunk; transposed PT output
    gemm_split<<<dim3(8, 32, 3), 256, 0, stream>>>(
        Ap0, 4096ull*2048, 2048, Bp0, 1024ull*2048,
        bq, bk, bv, PT0, 1, 3, 1);

    gather_qk  <<<16384, 256, 0, stream>>>(PT0,           Qp);
    gather_qk  <<<16384, 256, 0, stream>>>(PT0 + 4194304, Kp);
    v_transpose<<<dim3(32, 32), 256, 0, stream>>>(PT0 + 8388608, Vtp);

    split_bt<<<dim3(16, 16, 1), 256, 0, stream>>>(Wz, Wz, Wz, Bpz, 0);

    attn_mfma<<<dim3(512), 512, 0, stream>>>(Qp, Kp, Vtp, attn, Az);

    // out-GEMM: single chunk (Az bf16 compact stride 1024, Wz hi)
    gemm_split<<<dim3(8, 32, 1), 256, 0, stream>>>(
        Az, 0, 1024, Bpz, 0,
        bz, bz, bz, out0, 0, 1, 1);
}

// Round 8
// 821.864 us; speedup vs baseline: 1.5002x; 1.0140x over previous
//
#include <hip/hip_runtime.h>
#include <cstdint>
#include <cstddef>

// B=2, S=2048, E=1024, H=16, HD=64; rows = 4096; heads = 32.
//
// Precision tiers (validated r7, absmax 0.0156 vs 0.042 threshold):
//  - Q/K projections + QK^T: bf16 hi/lo split, 3 chunks.
//  - V projection, PV, out-GEMM: single bf16 chunk.
// r8: attn K/V double-buffered staging (issue jt+1 loads during jt compute;
// barrier's vmcnt(0) drain then waits on loads issued a full tile earlier),
// per-sub softmax processing (lower reg liveness), launch fusion 9->5.

typedef __bf16 bf16x4 __attribute__((ext_vector_type(4)));
typedef __bf16 bf16x8 __attribute__((ext_vector_type(8)));
typedef float floatx4 __attribute__((ext_vector_type(4)));

#define GLOAD_LDS16(g, l)                                                      \
    __builtin_amdgcn_global_load_lds(                                          \
        (const __attribute__((address_space(1))) void*)(g),                    \
        (__attribute__((address_space(3))) void*)(l), 16, 0, 0)

// ------------------------------------------------------------------
// prep: fused input preprocessing.
//  blocks [0, 12288): split_a — X fp32 -> Ap bf16 [hi|lo] rows (z = b/4096)
//  blocks [12288, 12288+256*nW): split_bt — W fp32 -> Bp bf16 [hi|lo] cols
//    slice 0..2 -> Bp0 + slice*1024*2048 ; slice 3 -> BpzDst (ws scratch)
// ------------------------------------------------------------------
__global__ __launch_bounds__(256) void prep(
    const float* __restrict__ x0, const float* __restrict__ x1,
    const float* __restrict__ x2, __bf16* __restrict__ ApBase,
    const float* __restrict__ w0, const float* __restrict__ w1,
    const float* __restrict__ w2, const float* __restrict__ w3,
    __bf16* __restrict__ Bp0, __bf16* __restrict__ BpzDst, int nW)
{
    const int flat = (int)blockIdx.x;
    const int tid = (int)threadIdx.x;

    if (flat < 12288) {
        const int z = flat >> 12;            // /4096
        const int bx = flat & 4095;
        const float* X = z == 0 ? x0 : (z == 1 ? x1 : x2);
        __bf16* Ap = ApBase + (size_t)z * (4096ull * 2048);
        const int idx = bx * 256 + tid;
        const int r = idx >> 8;
        const int c = (idx & 255) * 4;
        float4 t = *(const float4*)(X + (size_t)r * 1024 + c);
        bf16x4 hi, lo;
        hi[0] = (__bf16)t.x; lo[0] = (__bf16)(t.x - (float)hi[0]);
        hi[1] = (__bf16)t.y; lo[1] = (__bf16)(t.y - (float)hi[1]);
        hi[2] = (__bf16)t.z; lo[2] = (__bf16)(t.z - (float)hi[2]);
        hi[3] = (__bf16)t.w; lo[3] = (__bf16)(t.w - (float)hi[3]);
        *(bf16x4*)(Ap + (size_t)r * 2048 + c) = hi;
        *(bf16x4*)(Ap + (size_t)r * 2048 + 1024 + c) = lo;
        return;
    }

    const int t = flat - 12288;
    const int slice = t >> 8;
    if (slice >= nW) return;
    const int idx = t & 255;
    const float* W = slice == 0 ? w0 : (slice == 1 ? w1 : (slice == 2 ? w2 : w3));
    __bf16* Bp = slice < 3 ? (Bp0 + (size_t)slice * (1024ull * 2048)) : BpzDst;

    __shared__ float tile[64][65];
    const int k0 = (idx >> 4) * 64, n0 = (idx & 15) * 64;
    #pragma unroll
    for (int p = 0; p < 4; ++p) {
        int kr = p * 16 + (tid >> 4);
        float4 v = *(const float4*)(W + (size_t)(k0 + kr) * 1024 + n0 + (tid & 15) * 4);
        tile[kr][(tid & 15) * 4 + 0] = v.x; tile[kr][(tid & 15) * 4 + 1] = v.y;
        tile[kr][(tid & 15) * 4 + 2] = v.z; tile[kr][(tid & 15) * 4 + 3] = v.w;
    }
    __syncthreads();
    const int nr = tid >> 2, kc = (tid & 3) * 16;
    bf16x8 hi0, hi1, lo0, lo1;
    #pragma unroll
    for (int j = 0; j < 8; ++j) {
        float x = tile[kc + j][nr];
        __bf16 h = (__bf16)x; hi0[j] = h; lo0[j] = (__bf16)(x - (float)h);
        float y = tile[kc + 8 + j][nr];
        __bf16 g = (__bf16)y; hi1[j] = g; lo1[j] = (__bf16)(y - (float)g);
    }
    __bf16* row = Bp + (size_t)(n0 + nr) * 2048;
    *(bf16x8*)(row + k0 + kc)            = hi0;
    *(bf16x8*)(row + k0 + kc + 8)        = hi1;
    *(bf16x8*)(row + 1024 + k0 + kc)     = lo0;
    *(bf16x8*)(row + 1024 + k0 + kc + 8) = lo1;
}

// standalone Wz split for small-ws fallback (writes d_in[4] after prep)
__global__ __launch_bounds__(256) void split_bt1(
    const float* __restrict__ W, __bf16* __restrict__ Bp)
{
    __shared__ float tile[64][65];
    const int tid = (int)threadIdx.x;
    const int k0 = blockIdx.y * 64, n0 = blockIdx.x * 64;
    #pragma unroll
    for (int p = 0; p < 4; ++p) {
        int kr = p * 16 + (tid >> 4);
        float4 v = *(const float4*)(W + (size_t)(k0 + kr) * 1024 + n0 + (tid & 15) * 4);
        tile[kr][(tid & 15) * 4 + 0] = v.x; tile[kr][(tid & 15) * 4 + 1] = v.y;
        tile[kr][(tid & 15) * 4 + 2] = v.z; tile[kr][(tid & 15) * 4 + 3] = v.w;
    }
    __syncthreads();
    const int nr = tid >> 2, kc = (tid & 3) * 16;
    bf16x8 hi0, hi1, lo0, lo1;
    #pragma unroll
    for (int j = 0; j < 8; ++j) {
        float x = tile[kc + j][nr];
        __bf16 h = (__bf16)x; hi0[j] = h; lo0[j] = (__bf16)(x - (float)h);
        float y = tile[kc + 8 + j][nr];
        __bf16 g = (__bf16)y; hi1[j] = g; lo1[j] = (__bf16)(y - (float)g);
    }
    __bf16* row = Bp + (size_t)(n0 + nr) * 2048;
    *(bf16x8*)(row + k0 + kc)            = hi0;
    *(bf16x8*)(row + k0 + kc + 8)        = hi1;
    *(bf16x8*)(row + 1024 + k0 + kc)     = lo0;
    *(bf16x8*)(row + 1024 + k0 + kc + 8) = lo1;
}

// ------------------------------------------------------------------
// gemm_split: C(4096x1024) = A*B (+bias); fused multi-chunk K-loop.
// nch per z: (z==2) ? chunksV : chunksQK.
// ------------------------------------------------------------------
__global__ __launch_bounds__(256) void gemm_split(
    const __bf16* __restrict__ Ap0, size_t aSlice, int aStride,
    const __bf16* __restrict__ Bp0, size_t bSlice,
    const float* __restrict__ b0, const float* __restrict__ b1,
    const float* __restrict__ b2, float* __restrict__ Out0,
    int transposeOut, int chunksQK, int chunksV)
{
    const int z = blockIdx.z;
    const int nch = (z == 2) ? chunksV : chunksQK;
    const __bf16* Ap = Ap0 + (size_t)z * aSlice;
    const __bf16* Bp = Bp0 + (size_t)z * bSlice;
    const float* bias = z == 0 ? b0 : (z == 1 ? b1 : b2);
    float* Out = Out0 + (size_t)z * (4096ull * 1024);

    __shared__ __bf16 As[2 * 128 * 32];
    __shared__ __bf16 Bs[2 * 128 * 32];

    const int tid = (int)threadIdx.x;
    const int wave = tid >> 6, lane = tid & 63;
    const int quad = lane >> 4, tl = lane & 15;
    const int m0 = blockIdx.y * 128, n0 = blockIdx.x * 128;
    const int waveM = wave >> 1, waveN = wave & 1;

    floatx4 acc[4][4];
    #pragma unroll
    for (int i = 0; i < 4; ++i)
        #pragma unroll
        for (int j = 0; j < 4; ++j)
            acc[i][j] = (floatx4){0.f, 0.f, 0.f, 0.f};

    const int sRow  = (wave << 4) + (lane >> 2);
    const int sColB = (lane & 3) << 4;
    auto* AsL = (__attribute__((address_space(3))) char*)As;
    auto* BsL = (__attribute__((address_space(3))) char*)Bs;
    const int ldsOff = wave * 1024;

    for (int k0 = 0; k0 < 1024; k0 += 32) {
        __syncthreads();
        #pragma unroll
        for (int i = 0; i < 2; ++i) {
            GLOAD_LDS16((const char*)(Ap + (size_t)(m0 + i*64 + sRow) * aStride + k0) + sColB,
                        AsL + i * 4096 + ldsOff);
            GLOAD_LDS16((const char*)(Bp + (size_t)(n0 + i*64 + sRow) * 2048 + k0) + sColB,
                        BsL + i * 4096 + ldsOff);
            if (nch > 1) {
                GLOAD_LDS16((const char*)(Ap + 1024 + (size_t)(m0 + i*64 + sRow) * aStride + k0) + sColB,
                            AsL + 8192 + i * 4096 + ldsOff);
                GLOAD_LDS16((const char*)(Bp + 1024 + (size_t)(n0 + i*64 + sRow) * 2048 + k0) + sColB,
                            BsL + 8192 + i * 4096 + ldsOff);
            }
        }
        __syncthreads();

        bf16x8 ah[4], bh[4], al[4], bl[4];
        #pragma unroll
        for (int mt = 0; mt < 4; ++mt)
            ah[mt] = *(const bf16x8*)(As + (waveM*64 + mt*16 + tl) * 32 + quad * 8);
        #pragma unroll
        for (int nt = 0; nt < 4; ++nt)
            bh[nt] = *(const bf16x8*)(Bs + (waveN*64 + nt*16 + tl) * 32 + quad * 8);
        #pragma unroll
        for (int mt = 0; mt < 4; ++mt)
            #pragma unroll
            for (int nt = 0; nt < 4; ++nt)
                acc[mt][nt] = __builtin_amdgcn_mfma_f32_16x16x32_bf16(
                    ah[mt], bh[nt], acc[mt][nt], 0, 0, 0);
        if (nch > 1) {
            #pragma unroll
            for (int mt = 0; mt < 4; ++mt)
                al[mt] = *(const bf16x8*)(As + 4096 + (waveM*64 + mt*16 + tl) * 32 + quad * 8);
            #pragma unroll
            for (int mt = 0; mt < 4; ++mt)
                #pragma unroll
                for (int nt = 0; nt < 4; ++nt)
                    acc[mt][nt] = __builtin_amdgcn_mfma_f32_16x16x32_bf16(
                        al[mt], bh[nt], acc[mt][nt], 0, 0, 0);
        }
        if (nch > 2) {
            #pragma unroll
            for (int nt = 0; nt < 4; ++nt)
                bl[nt] = *(const bf16x8*)(Bs + 4096 + (waveN*64 + nt*16 + tl) * 32 + quad * 8);
            #pragma unroll
            for (int mt = 0; mt < 4; ++mt)
                #pragma unroll
                for (int nt = 0; nt < 4; ++nt)
                    acc[mt][nt] = __builtin_amdgcn_mfma_f32_16x16x32_bf16(
                        ah[mt], bl[nt], acc[mt][nt], 0, 0, 0);
        }
    }

    if (transposeOut) {
        #pragma unroll
        for (int nt = 0; nt < 4; ++nt) {
            const int e = n0 + waveN * 64 + nt * 16 + tl;
            const float bb = bias[e];
            #pragma unroll
            for (int mt = 0; mt < 4; ++mt) {
                floatx4 v = acc[mt][nt] + bb;
                *(floatx4*)(Out + (size_t)e * 4096 + m0 + waveM * 64 + mt * 16 + quad * 4) = v;
            }
        }
    } else {
        #pragma unroll
        for (int mt = 0; mt < 4; ++mt) {
            const int rbase = m0 + waveM * 64 + mt * 16 + quad * 4;
            #pragma unroll
            for (int nt = 0; nt < 4; ++nt) {
                const int e = n0 + waveN * 64 + nt * 16 + tl;
                const float bb = bias[e];
                #pragma unroll
                for (int reg = 0; reg < 4; ++reg)
                    Out[(size_t)(rbase + reg) * 1024 + e] = acc[mt][nt][reg] + bb;
            }
        }
    }
}

// ------------------------------------------------------------------
// gather_all: fused head-gather (Q, K normalized hi/lo) + V transpose.
//  blocks [0,16384): Q ; [16384,32768): K ; [32768,33792): v_transpose
// ------------------------------------------------------------------
__global__ __launch_bounds__(256) void gather_all(
    const float* __restrict__ PT0, __bf16* __restrict__ Qp,
    __bf16* __restrict__ Kp, __bf16* __restrict__ Vt)
{
    const int flat = (int)blockIdx.x;
    const int tid = (int)threadIdx.x;

    if (flat < 32768) {
        const float* PT = flat < 16384 ? PT0 : (PT0 + 4194304);
        __bf16* Outp = flat < 16384 ? Qp : Kp;
        const int bx = flat & 16383;
        const int lane = tid & 63;
        const int vec  = bx * 4 + (tid >> 6);
        const int head = vec >> 11;
        const int sp   = vec & 2047;
        const int c    = (head >> 4) * 512 + (head & 15) * 32 + (sp >> 6);
        const int src  = (lane & 1) * 2048 + (sp & 63) * 32 + (lane >> 1);
        float v = PT[(size_t)c * 4096 + src];
        float ss = v * v;
        #pragma unroll
        for (int mk = 32; mk >= 1; mk >>= 1) ss += __shfl_xor(ss, mk);
        v = v / sqrtf(ss);
        __bf16 h = (__bf16)v;
        Outp[(size_t)vec * 128 + lane]      = h;
        Outp[(size_t)vec * 128 + 64 + lane] = (__bf16)(v - (float)h);
        return;
    }

    // v_transpose: PTv[e][4096] -> Vt[head][d=64][2048] bf16 (hi only)
    const int t = flat - 32768;           // 0..1023
    const int st = t & 31, head = t >> 5;
    const float* PTv = PT0 + 8388608;
    const int c = (head >> 4) * 512 + (head & 15) * 32 + st;
    const float* __restrict__ row = PTv + (size_t)c * 4096;

    __shared__ float tile[64][65];
    #pragma unroll
    for (int i = 0; i < 4; ++i) {
        int o = i * 1024 + tid * 4;
        float4 v4 = *(const float4*)(row + o);
        float vals[4] = {v4.x, v4.y, v4.z, v4.w};
        #pragma unroll
        for (int e = 0; e < 4; ++e) {
            int oo = o + e;
            int d  = ((oo & 2047) & 31) * 2 + (oo >> 11);
            int sl = (oo & 2047) >> 5;
            tile[sl][d] = vals[e];
        }
    }
    __syncthreads();

    const int d = tid >> 2, jb = (tid & 3) * 16;
    bf16x8 h0, h1;
    #pragma unroll
    for (int j = 0; j < 8; ++j) {
        h0[j] = (__bf16)tile[jb + j][d];
        h1[j] = (__bf16)tile[jb + 8 + j][d];
    }
    size_t bh = ((size_t)head * 64 + d) * 2048 + st * 64 + jb;
    *(bf16x8*)(Vt + bh)     = h0;
    *(bf16x8*)(Vt + bh + 8) = h1;
}

// ------------------------------------------------------------------
// attn_mfma: block = (128 i-rows, head); 8 waves x 16 rows, 512 threads.
// QK^T: 3-chunk hi/lo. PV: single chunk. K/V staged via global_load_lds
// (XOR chunk swizzle) with DOUBLE BUFFERING: tile jt+1's loads are issued
// right after the barrier publishing jt, so the next barrier's vmcnt(0)
// drain waits on loads that flew during a full compute phase.
// ------------------------------------------------------------------
__global__ __launch_bounds__(512, 4) void attn_mfma(
    const __bf16* __restrict__ Qp, const __bf16* __restrict__ Kp,
    const __bf16* __restrict__ Vt, float* __restrict__ Attn,
    __bf16* __restrict__ Az)
{
    const int flat = (int)blockIdx.x;
    const int head = flat & 31;
    const int it   = 15 - (flat >> 5);     // heavy tiles dispatch first
    const int tid = (int)threadIdx.x;
    const int w = tid >> 6, lane = tid & 63;
    const int quad = lane >> 4, tl = lane & 15;
    const int t7 = tl & 7;
    const int i0 = it * 128;
    const int jtmax = 2 * it + 1;                  // always odd
    const int wrowMax = i0 + w * 16 + 15;
    const int wdiag   = (i0 + w * 16) >> 6;
    const int irowBase = w * 16 + quad * 4;

    const __bf16* __restrict__ Qh = Qp + ((size_t)head * 2048 + i0) * 128;
    const __bf16* __restrict__ Kh = Kp + (size_t)head * 2048 * 128;
    const __bf16* __restrict__ Vh = Vt + (size_t)head * 64 * 2048;
    float* __restrict__ Ah = Attn + (size_t)head * ((size_t)2048 * 2048);

    __shared__ __bf16 kb[2][64 * 128];   // K tile dbuf (2 x 16 KB)
    __shared__ __bf16 vt[2][64 * 64];    // V^T tile dbuf (2 x 8 KB)
    __shared__ __bf16 ps[8][16 * 72];    // wave-private P staging (18 KB)
    __bf16* psw = ps[w];
    auto* kbL = (__attribute__((address_space(3))) char*)&kb[0][0];
    auto* vtL = (__attribute__((address_space(3))) char*)&vt[0][0];

    // per-lane staging sources (swizzled)
    const char* kSrc[2];
    #pragma unroll
    for (int i = 0; i < 2; ++i) {
        int d  = i * 512 + tid;
        int rK = d >> 4, cK = (d & 15) ^ (rK & 7);
        kSrc[i] = (const char*)(Kh + (size_t)rK * 128) + cK * 16;
    }
    const char* vSrc;
    {
        int rV = tid >> 3, cV = (tid & 7) ^ (rV & 7);
        vSrc = (const char*)(Vh + (size_t)rV * 2048) + cV * 16;
    }
    const int ok0 = ((quad)      ^ t7) * 8;
    const int ok1 = ((quad + 4)  ^ t7) * 8;
    const int ok2 = ((quad + 8)  ^ t7) * 8;
    const int ok3 = ((quad + 12) ^ t7) * 8;

    // Q fragments direct from global (once per block)
    const __bf16* qrow = Qh + (size_t)(w * 16 + tl) * 128;
    bf16x8 qhi0 = *(const bf16x8*)(qrow + quad * 8);
    bf16x8 qhi1 = *(const bf16x8*)(qrow + 32 + quad * 8);
    bf16x8 qlo0 = *(const bf16x8*)(qrow + 64 + quad * 8);
    bf16x8 qlo1 = *(const bf16x8*)(qrow + 96 + quad * 8);

    // tiles beyond jtmax: exact zeros
    for (int jt = jtmax + 1; jt < 32; ++jt) {
        float4 z4 = make_float4(0.f, 0.f, 0.f, 0.f);
        #pragma unroll
        for (int g = 0; g < 4; ++g)
            *(float4*)(Ah + (size_t)(i0 + w * 16 + g * 4 + quad) * 2048
                          + jt * 64 + tl * 4) = z4;
    }

    float m[4], l[4];
    #pragma unroll
    for (int r = 0; r < 4; ++r) { m[r] = -3.0e38f; l[r] = 0.0f; }

    // ---------- pass 1: stats (K dbuf) ----------
    #pragma unroll
    for (int i = 0; i < 2; ++i)                       // prologue: jt=0 -> kb[0]
        GLOAD_LDS16(kSrc[i], kbL + i * 8192 + w * 1024);

    for (int jt = 0; jt <= jtmax; ++jt) {
        const int cur = jt & 1;
        __syncthreads();                              // publishes kb[cur]
        if (jt < jtmax) {                             // issue jt+1 -> kb[cur^1]
            #pragma unroll
            for (int i = 0; i < 2; ++i)
                GLOAD_LDS16(kSrc[i] + (size_t)(jt + 1) * 16384,
                            kbL + (cur ^ 1) * 16384 + i * 8192 + w * 1024);
        }
        if (jt * 64 > wrowMax) continue;              // fully masked (wave-uniform)

        const __bf16* kbuf = &kb[cur][0];
        const bool diag = (jt == wdiag);
        #pragma unroll
        for (int sub = 0; sub < 4; ++sub) {
            const __bf16* kr = kbuf + (sub * 16 + tl) * 128;
            bf16x8 khi0 = *(const bf16x8*)(kr + ok0);
            bf16x8 khi1 = *(const bf16x8*)(kr + ok1);
            bf16x8 klo0 = *(const bf16x8*)(kr + ok2);
            bf16x8 klo1 = *(const bf16x8*)(kr + ok3);
            floatx4 s = (floatx4){0.f, 0.f, 0.f, 0.f};
            s = __builtin_amdgcn_mfma_f32_16x16x32_bf16(qhi0, khi0, s, 0, 0, 0);
            s = __builtin_amdgcn_mfma_f32_16x16x32_bf16(qhi1, khi1, s, 0, 0, 0);
            s = __builtin_amdgcn_mfma_f32_16x16x32_bf16(qhi0, klo0, s, 0, 0, 0);
            s = __builtin_amdgcn_mfma_f32_16x16x32_bf16(qhi1, klo1, s, 0, 0, 0);
            s = __builtin_amdgcn_mfma_f32_16x16x32_bf16(qlo0, khi0, s, 0, 0, 0);
            s = __builtin_amdgcn_mfma_f32_16x16x32_bf16(qlo1, khi1, s, 0, 0, 0);
            const int col = jt * 64 + sub * 16 + tl;
            #pragma unroll
            for (int reg = 0; reg < 4; ++reg) {
                float lv = s[reg] * 1000.0f;
                if (diag && (col > i0 + irowBase + reg)) lv = -1.0e9f;
                float mn = fmaxf(m[reg], lv);
                l[reg] = l[reg] * __expf(m[reg] - mn) + __expf(lv - mn);
                m[reg] = mn;
            }
        }
    }

    // reduce stats across the 16 tl lanes
    #pragma unroll
    for (int reg = 0; reg < 4; ++reg) {
        #pragma unroll
        for (int mk = 8; mk >= 1; mk >>= 1) {
            float mo = __shfl_xor(m[reg], mk);
            float lo = __shfl_xor(l[reg], mk);
            float mn = fmaxf(m[reg], mo);
            l[reg] = l[reg] * __expf(m[reg] - mn) + lo * __expf(mo - mn);
            m[reg] = mn;
        }
    }
    float inv_l[4];
    #pragma unroll
    for (int reg = 0; reg < 4; ++reg) inv_l[reg] = 1.0f / l[reg];

    // ---------- pass 2: attn write + PV (K+V dbuf) ----------
    floatx4 zacc[4];
    #pragma unroll
    for (int t = 0; t < 4; ++t) zacc[t] = (floatx4){0.f, 0.f, 0.f, 0.f};

    // prologue: jt=0 -> kb[0], vt[0]. Safe: pass-1's last compute used
    // kb[jtmax&1] = kb[1] (jtmax odd), and all waves passed that barrier.
    #pragma unroll
    for (int i = 0; i < 2; ++i)
        GLOAD_LDS16(kSrc[i], kbL + i * 8192 + w * 1024);
    GLOAD_LDS16(vSrc, vtL + w * 1024);

    for (int jt = 0; jt <= jtmax; ++jt) {
        const int cur = jt & 1;
        __syncthreads();                              // publishes kb/vt[cur]
        if (jt < jtmax) {
            #pragma unroll
            for (int i = 0; i < 2; ++i)
                GLOAD_LDS16(kSrc[i] + (size_t)(jt + 1) * 16384,
                            kbL + (cur ^ 1) * 16384 + i * 8192 + w * 1024);
            GLOAD_LDS16(vSrc + (size_t)(jt + 1) * 128,
                        vtL + (cur ^ 1) * 8192 + w * 1024);
        }

        if (jt * 64 > wrowMax) {                      // fully masked: zeros
            float4 z4 = make_float4(0.f, 0.f, 0.f, 0.f);
            #pragma unroll
            for (int g = 0; g < 4; ++g)
                *(float4*)(Ah + (size_t)(i0 + w * 16 + g * 4 + quad) * 2048
                              + jt * 64 + tl * 4) = z4;
            continue;
        }

        const __bf16* kbuf = &kb[cur][0];
        const __bf16* vbuf = &vt[cur][0];
        const bool diag = (jt == wdiag);
        #pragma unroll
        for (int sub = 0; sub < 4; ++sub) {
            const __bf16* kr = kbuf + (sub * 16 + tl) * 128;
            bf16x8 khi0 = *(const bf16x8*)(kr + ok0);
            bf16x8 khi1 = *(const bf16x8*)(kr + ok1);
            bf16x8 klo0 = *(const bf16x8*)(kr + ok2);
            bf16x8 klo1 = *(const bf16x8*)(kr + ok3);
            floatx4 s = (floatx4){0.f, 0.f, 0.f, 0.f};
            s = __builtin_amdgcn_mfma_f32_16x16x32_bf16(qhi0, khi0, s, 0, 0, 0);
            s = __builtin_amdgcn_mfma_f32_16x16x32_bf16(qhi1, khi1, s, 0, 0, 0);
            s = __builtin_amdgcn_mfma_f32_16x16x32_bf16(qhi0, klo0, s, 0, 0, 0);
            s = __builtin_amdgcn_mfma_f32_16x16x32_bf16(qhi1, klo1, s, 0, 0, 0);
            s = __builtin_amdgcn_mfma_f32_16x16x32_bf16(qlo0, khi0, s, 0, 0, 0);
            s = __builtin_amdgcn_mfma_f32_16x16x32_bf16(qlo1, khi1, s, 0, 0, 0);
            const int col = jt * 64 + sub * 16 + tl;
            #pragma unroll
            for (int reg = 0; reg < 4; ++reg) {
                float lv = s[reg] * 1000.0f;
                if (diag && (col > i0 + irowBase + reg)) lv = -1.0e9f;
                float p = __expf(lv - m[reg]) * inv_l[reg];
                psw[(quad * 4 + reg) * 72 + sub * 16 + tl] = (__bf16)p;
            }
        }
        // wave-private LDS: wait for writes (cross-lane reads next)
        __asm__ volatile("s_waitcnt lgkmcnt(0)" ::: "memory");

        // coalesced attn stores
        #pragma unroll
        for (int g = 0; g < 4; ++g) {
            bf16x4 pv = *(const bf16x4*)(psw + (g * 4 + quad) * 72 + tl * 4);
            float4 f = make_float4((float)pv[0], (float)pv[1],
                                   (float)pv[2], (float)pv[3]);
            *(float4*)(Ah + (size_t)(i0 + w * 16 + g * 4 + quad) * 2048
                          + jt * 64 + tl * 4) = f;
        }

        // P A-fragments, then PV MFMA (V hi only)
        bf16x8 p0 = *(const bf16x8*)(psw + tl * 72 + quad * 8);
        bf16x8 p1 = *(const bf16x8*)(psw + tl * 72 + 32 + quad * 8);
        #pragma unroll
        for (int t = 0; t < 4; ++t) {
            const __bf16* vh0 = vbuf + (t * 16 + tl) * 64;
            bf16x8 vhi0 = *(const bf16x8*)(vh0 + ok0);
            bf16x8 vhi1 = *(const bf16x8*)(vh0 + ok1);
            zacc[t] = __builtin_amdgcn_mfma_f32_16x16x32_bf16(p0, vhi0, zacc[t], 0, 0, 0);
            zacc[t] = __builtin_amdgcn_mfma_f32_16x16x32_bf16(p1, vhi1, zacc[t], 0, 0, 0);
        }
    }

    // epilogue: z -> Az bf16 (single chunk)
    const int b = head >> 4, h = head & 15;
    #pragma unroll
    for (int reg = 0; reg < 4; ++reg) {
        const size_t R = (size_t)b * 2048 + i0 + w * 16 + quad * 4 + reg;
        #pragma unroll
        for (int t = 0; t < 4; ++t)
            Az[R * 1024 + h * 64 + t * 16 + tl] = (__bf16)zacc[t][reg];
    }
}

// ------------------------------------------------------------------
extern "C" void kernel_launch(void* const* d_in, const int* in_sizes, int n_in,
                              void* d_out, int out_size, void* d_ws, size_t ws_size,
                              hipStream_t stream) {
    (void)in_sizes; (void)n_in; (void)out_size;
    const float* q  = (const float*)d_in[0];
    const float* k  = (const float*)d_in[1];
    const float* v  = (const float*)d_in[2];
    const float* Wq = (const float*)d_in[4];  const float* bq = (const float*)d_in[5];
    const float* Wk = (const float*)d_in[6];  const float* bk = (const float*)d_in[7];
    const float* Wv = (const float*)d_in[8];  const float* bv = (const float*)d_in[9];
    const float* Wz = (const float*)d_in[10]; const float* bz = (const float*)d_in[11];

    float* out0 = (float*)d_out;               // (2,2048,1024)
    float* attn = out0 + 4194304;              // (2,16,2048,2048) = 512 MB

    // Scratch in the not-yet-written attn region:
    float*  PT0 = attn;                                   // 3 x 4M floats
    __bf16* Ap0 = (__bf16*)(attn + 12582912);             // 3 x 4096x2048 bf16
    __bf16* Bp0 = (__bf16*)(attn + 12582912 + 12582912);  // 3 x 1024x2048 bf16

    // ws layout (big path): Qp 16MB | Kp 16MB | Vt 8MB | Az 8MB | Bpz 4MB
    __bf16 *Qp, *Kp, *Vtp, *Az, *Bpz;
    const bool bigWs = ws_size >= (size_t)54525952;   // 52 MB
    if (bigWs) {
        __bf16* ws = (__bf16*)d_ws;
        Qp = ws; Kp = ws + 8388608; Vtp = ws + 16777216; Az = ws + 20971520;
        Bpz = ws + 25165824;
    } else {
        Qp = (__bf16*)d_in[0]; Kp = (__bf16*)d_in[1]; Vtp = (__bf16*)d_in[2];
        Az = (__bf16*)d_ws;
        Bpz = (__bf16*)d_in[4];   // written by separate launch after prep
    }

    // prep: split_a (12288 blocks) + weight splits (256/slice)
    if (bigWs) {
        prep<<<dim3(12288 + 4 * 256), 256, 0, stream>>>(
            q, k, v, Ap0, Wq, Wk, Wv, Wz, Bp0, Bpz, 4);
    } else {
        prep<<<dim3(12288 + 3 * 256), 256, 0, stream>>>(
            q, k, v, Ap0, Wq, Wk, Wv, Wz, Bp0, nullptr, 3);
        split_bt1<<<dim3(16, 16), 256, 0, stream>>>(Wz, Bpz);
    }

    // projections: Q/K 3-chunk, V 1-chunk; transposed PT output
    gemm_split<<<dim3(8, 32, 3), 256, 0, stream>>>(
        Ap0, 4096ull*2048, 2048, Bp0, 1024ull*2048,
        bq, bk, bv, PT0, 1, 3, 1);

    gather_all<<<dim3(33792), 256, 0, stream>>>(PT0, Qp, Kp, Vtp);

    attn_mfma<<<dim3(512), 512, 0, stream>>>(Qp, Kp, Vtp, attn, Az);

    // out-GEMM: single chunk (Az bf16 compact stride 1024, Wz hi)
    gemm_split<<<dim3(8, 32, 1), 256, 0, stream>>>(
        Az, 0, 1024, Bpz, 0,
        bz, bz, bz, out0, 0, 1, 1);
}